// Round 11
// baseline (929.788 us; speedup 1.0000x reference)
//
#include <hip/hip_runtime.h>
#include <hip/hip_bf16.h>
#include <math.h>

#define LDIM 384
#define CDIM 128
#define HN 4
#define LL (LDIM*LDIM)
#define NCHUNK 8
#define VTPLANE ((size_t)12288*384)

typedef __attribute__((ext_vector_type(8))) short bf16x8;
typedef __attribute__((ext_vector_type(4))) float f32x4;

__device__ __forceinline__ ushort f2bf(float x) {
    union { __hip_bfloat16 h; ushort u; } cv;
    cv.h = __float2bfloat16(x);
    return cv.u;
}
__device__ __forceinline__ float bf2f(ushort u) {
    union { unsigned int i; float f; } cv; cv.i = ((unsigned int)u) << 16; return cv.f;
}
__device__ __forceinline__ int swz256(int row, int cb) { return (row * 256 + cb) ^ ((row & 7) << 4); }
__device__ __forceinline__ int swz128(int row, int cb) { return (row * 128 + cb) ^ ((row & 7) << 4); }
__device__ __forceinline__ size_t trow(int row) { return (size_t)(row % LDIM) * LDIM + row / LDIM; }

// ---------------- weight prep: fp32 [K][N] -> bf16 [N][KP] (zero-padded K) ----------------
__global__ __launch_bounds__(256) void wprep_kernel(ushort* __restrict__ wt,
    const float* emb_w, const float* proj_w,
    const float* rwq, const float* rwk, const float* rwv, const float* rwg, const float* rwo,
    const float* cwq, const float* cwk, const float* cwv, const float* cwg, const float* cwo,
    const float* ffw1, const float* ffw2)
{
    int y = blockIdx.y;
    const float* src; int N, K, KP; size_t off;
    switch (y) {
        case 0:  src = emb_w;  N = 128; K = 36;  KP = 128; off = 0;         break;
        case 1:  src = proj_w; N = 128; K = 128; KP = 128; off = 16384;     break;
        case 2:  src = rwq;    N = 128; K = 128; KP = 128; off = 2*16384;   break;
        case 3:  src = rwk;    N = 128; K = 128; KP = 128; off = 3*16384;   break;
        case 4:  src = rwv;    N = 128; K = 128; KP = 128; off = 4*16384;   break;
        case 5:  src = rwg;    N = 128; K = 128; KP = 128; off = 5*16384;   break;
        case 6:  src = rwo;    N = 128; K = 128; KP = 128; off = 6*16384;   break;
        case 7:  src = cwq;    N = 128; K = 128; KP = 128; off = 7*16384;   break;
        case 8:  src = cwk;    N = 128; K = 128; KP = 128; off = 8*16384;   break;
        case 9:  src = cwv;    N = 128; K = 128; KP = 128; off = 9*16384;   break;
        case 10: src = cwg;    N = 128; K = 128; KP = 128; off = 10*16384;  break;
        case 11: src = cwo;    N = 128; K = 128; KP = 128; off = 11*16384;  break;
        case 12: src = ffw1;   N = 256; K = 128; KP = 128; off = 12*16384;  break;
        default: src = ffw2;   N = 128; K = 256; KP = 256; off = 12*16384 + 32768; break;
    }
    int e = blockIdx.x * 256 + threadIdx.x;
    if (e >= N * KP) return;
    int nn = e / KP, kp = e - nn * KP;
    float v = (kp < K) ? src[(size_t)kp * N + nn] : 0.f;
    wt[off + e] = f2bf(v);
}

// ------- LN + bf16 pack: coalesced read of src row p, write to dst row trans(p) -------
__global__ __launch_bounds__(256) void lnpack_kernel(const float* __restrict__ src,
    ushort* __restrict__ dst, const float* __restrict__ w, const float* __restrict__ b, int trans)
{
    int p = (blockIdx.x << 2) + (threadIdx.x >> 6);
    int lane = threadIdx.x & 63;
    float2 v = *(const float2*)(src + (size_t)p * CDIM + (lane << 1));
    float s  = v.x + v.y;
    float ss = v.x*v.x + v.y*v.y;
    #pragma unroll
    for (int off = 32; off; off >>= 1) { s += __shfl_xor(s, off, 64); ss += __shfl_xor(ss, off, 64); }
    float mean = s * (1.0f/CDIM);
    float var  = ss * (1.0f/CDIM) - mean*mean;
    float rstd = rsqrtf(var + 1e-5f);
    int q = trans ? ((p % LDIM) * LDIM + p / LDIM) : p;
    ushort2 o;
    o.x = f2bf((v.x - mean) * rstd * w[lane<<1]     + b[lane<<1]);
    o.y = f2bf((v.y - mean) * rstd * w[(lane<<1)+1] + b[(lane<<1)+1]);
    *(ushort2*)(dst + (size_t)q * CDIM + (lane << 1)) = o;
}

// ------- bias-attention: coalesced read rbf row p=(a,b); write battn[h,i,j] (trans swaps) -------
__global__ __launch_bounds__(256) void battn_kernel(const float* __restrict__ rbf,
    float* __restrict__ battn, const float* __restrict__ lnw, const float* __restrict__ lnb,
    const float* __restrict__ wb, int trans)
{
    int p = (blockIdx.x << 2) + (threadIdx.x >> 6);
    int lane = threadIdx.x & 63;
    int a = p / LDIM, b2 = p % LDIM;
    float2 v = *(const float2*)(rbf + (size_t)p * CDIM + (lane << 1));
    float s = v.x + v.y, ss = v.x*v.x + v.y*v.y;
    #pragma unroll
    for (int off = 32; off; off >>= 1) { s += __shfl_xor(s, off, 64); ss += __shfl_xor(ss, off, 64); }
    float mean = s*(1.f/CDIM), var = ss*(1.f/CDIM) - mean*mean, rstd = rsqrtf(var + 1e-5f);
    float x0 = (v.x - mean)*rstd*lnw[lane<<1]     + lnb[lane<<1];
    float x1 = (v.y - mean)*rstd*lnw[(lane<<1)+1] + lnb[(lane<<1)+1];
    int c0 = (lane<<1)*HN, c1 = ((lane<<1)+1)*HN;
    float a0 = x0*wb[c0+0] + x1*wb[c1+0];
    float a1 = x0*wb[c0+1] + x1*wb[c1+1];
    float a2 = x0*wb[c0+2] + x1*wb[c1+2];
    float a3 = x0*wb[c0+3] + x1*wb[c1+3];
    #pragma unroll
    for (int off = 32; off; off >>= 1) {
        a0 += __shfl_xor(a0, off, 64); a1 += __shfl_xor(a1, off, 64);
        a2 += __shfl_xor(a2, off, 64); a3 += __shfl_xor(a3, off, 64);
    }
    if (lane == 0) {
        int io = trans ? b2 : a, jo = trans ? a : b2;
        battn[((size_t)0*LDIM + io)*LDIM + jo] = a0;
        battn[((size_t)1*LDIM + io)*LDIM + jo] = a1;
        battn[((size_t)2*LDIM + io)*LDIM + jo] = a2;
        battn[((size_t)3*LDIM + io)*LDIM + jo] = a3;
    }
}

// ------- direct-B 128x128-tile MFMA GEMM: A staged in LDS (128-col chunks), B-fragments
//         read straight from global Wt[N][KP] (weights are L1/L2-resident). -------
// AMODE: 0 fp32, 1 bf16, 2 bf16 gated. OUTMODE: 0 fp32 (+res), 1 bf16, 3 fp32 w/ rtrans/otrans.
// LNOUT: fuse LN over 128 out channels (N=128, grid.x=1, OUTMODE3): writes out fp32 + xln bf16.
template<int ACT, int AMODE, int OUTMODE, int LNOUT>
__global__ __launch_bounds__(256) void dgemm128(
    const void* __restrict__ Ain, const ushort* __restrict__ Wt,
    const float* __restrict__ bias, const ushort* __restrict__ gmul,
    const float* __restrict__ res, void* __restrict__ Cout,
    const float* __restrict__ lnw2, const float* __restrict__ lnb2, ushort* __restrict__ xln,
    int N, int KP, int lda, float alpha, int rtrans, int otrans)
{
    __shared__ ushort As[128*128];   // 32 KB — only A staged
    int t = threadIdx.x, l = t & 63, wv = t >> 6;
    int m0 = blockIdx.y << 7, n0 = blockIdx.x << 7;
    int wm = (wv >> 1) << 6, wn = (wv & 1) << 6;
    int sr = t >> 1, scb = (t & 1) << 7;   // staging row, col-byte base (0/128)
    f32x4 acc[4][4] = {};
    for (int kt = 0; kt < KP; kt += 128) {
        if (kt) __syncthreads();
        if (AMODE == 1) {
            const ushort* ap = (const ushort*)Ain + (size_t)(m0 + sr) * lda + kt + (scb >> 1);
            #pragma unroll
            for (int u = 0; u < 8; u++)
                *(int4*)((char*)As + swz256(sr, scb + (u << 4))) = *(const int4*)(ap + (u << 3));
        } else if (AMODE == 2) {
            const ushort* ap = (const ushort*)Ain + (size_t)(m0 + sr) * lda + kt + (scb >> 1);
            const ushort* gp = gmul + (size_t)(m0 + sr) * lda + kt + (scb >> 1);
            #pragma unroll
            for (int u = 0; u < 8; u++) {
                int4 av = *(const int4*)(ap + (u << 3));
                int4 gv = *(const int4*)(gp + (u << 3));
                ushort* au = (ushort*)&av; ushort* gu = (ushort*)&gv;
                short v8[8];
                #pragma unroll
                for (int e = 0; e < 8; e++) v8[e] = (short)f2bf(bf2f(au[e]) * bf2f(gu[e]));
                *(int4*)((char*)As + swz256(sr, scb + (u << 4))) = *(int4*)v8;
            }
        } else {
            const float* ap = (const float*)Ain + (size_t)(m0 + sr) * lda;
            int cb0 = kt + (scb >> 1);
            #pragma unroll
            for (int u = 0; u < 8; u++) {
                short v8[8];
                #pragma unroll
                for (int e = 0; e < 8; e++) {
                    int c = cb0 + (u << 3) + e;
                    v8[e] = (short)f2bf((c < lda) ? ap[c] : 0.f);
                }
                *(int4*)((char*)As + swz256(sr, scb + (u << 4))) = *(int4*)v8;
            }
        }
        __syncthreads();
        #pragma unroll
        for (int ks = 0; ks < 4; ks++) {
            int kb = (ks << 6) + ((l >> 4) << 4);   // byte offset in As row
            int kw = kt + (kb >> 1);                // short offset in Wt row
            bf16x8 a[4], b[4];
            #pragma unroll
            for (int x = 0; x < 4; x++) {
                a[x] = *(const bf16x8*)((char*)As + swz256(wm + (x << 4) + (l & 15), kb));
                b[x] = *(const bf16x8*)(Wt + (size_t)(n0 + wn + (x << 4) + (l & 15)) * KP + kw);
            }
            #pragma unroll
            for (int i = 0; i < 4; i++)
            #pragma unroll
            for (int j = 0; j < 4; j++)
                acc[i][j] = __builtin_amdgcn_mfma_f32_16x16x32_bf16(a[i], b[j], acc[i][j], 0, 0, 0);
        }
    }
    if (LNOUT) {
        #pragma unroll
        for (int mf = 0; mf < 4; mf++)
        #pragma unroll
        for (int nf = 0; nf < 4; nf++) {
            int col  = wn + (nf << 4) + (l & 15);
            int row0 = m0 + wm + (mf << 4) + ((l >> 4) << 2);
            float bb = bias ? bias[col] : 0.f;
            #pragma unroll
            for (int r = 0; r < 4; r++) {
                int row = row0 + r;
                size_t rrow = rtrans ? trow(row) : (size_t)row;
                acc[mf][nf][r] = acc[mf][nf][r] * alpha + bb + (res ? res[rrow * CDIM + col] : 0.f);
            }
        }
        float ps[4][4], pq[4][4];
        #pragma unroll
        for (int mf = 0; mf < 4; mf++)
        #pragma unroll
        for (int r = 0; r < 4; r++) {
            float s = 0.f, q = 0.f;
            #pragma unroll
            for (int nf = 0; nf < 4; nf++) { float v = acc[mf][nf][r]; s += v; q += v * v; }
            ps[mf][r] = s; pq[mf][r] = q;
        }
        #pragma unroll
        for (int off = 1; off < 16; off <<= 1)
        #pragma unroll
        for (int mf = 0; mf < 4; mf++)
        #pragma unroll
        for (int r = 0; r < 4; r++) {
            ps[mf][r] += __shfl_xor(ps[mf][r], off, 64);
            pq[mf][r] += __shfl_xor(pq[mf][r], off, 64);
        }
        __syncthreads();
        float* lnbuf = (float*)As;       // [2][128][2]
        if ((l & 15) == 0) {
            #pragma unroll
            for (int mf = 0; mf < 4; mf++)
            #pragma unroll
            for (int r = 0; r < 4; r++) {
                int rl = wm + (mf << 4) + ((l >> 4) << 2) + r;
                lnbuf[(((wv & 1) << 7) + rl) * 2 + 0] = ps[mf][r];
                lnbuf[(((wv & 1) << 7) + rl) * 2 + 1] = pq[mf][r];
            }
        }
        __syncthreads();
        #pragma unroll
        for (int mf = 0; mf < 4; mf++)
        #pragma unroll
        for (int nf = 0; nf < 4; nf++) {
            int col  = wn + (nf << 4) + (l & 15);
            int row0 = m0 + wm + (mf << 4) + ((l >> 4) << 2);
            float lw = lnw2[col], lb = lnb2[col];
            #pragma unroll
            for (int r = 0; r < 4; r++) {
                int row = row0 + r;
                int rl  = wm + (mf << 4) + ((l >> 4) << 2) + r;
                float s  = lnbuf[rl * 2 + 0] + lnbuf[(256 + rl * 2) + 0];
                float q  = lnbuf[rl * 2 + 1] + lnbuf[(256 + rl * 2) + 1];
                float mean = s * (1.f/CDIM);
                float var  = q * (1.f/CDIM) - mean * mean;
                float rstd = rsqrtf(var + 1e-5f);
                float o = acc[mf][nf][r];
                size_t orow = otrans ? trow(row) : (size_t)row;
                ((float*)Cout)[orow * CDIM + col] = o;
                xln[orow * CDIM + col] = f2bf((o - mean) * rstd * lw + lb);
            }
        }
    } else {
        #pragma unroll
        for (int mf = 0; mf < 4; mf++)
        #pragma unroll
        for (int nf = 0; nf < 4; nf++) {
            int col  = n0 + wn + (nf << 4) + (l & 15);
            int row0 = m0 + wm + (mf << 4) + ((l >> 4) << 2);
            float bb = bias ? bias[col] : 0.f;
            #pragma unroll
            for (int r = 0; r < 4; r++) {
                int row = row0 + r;
                float v = acc[mf][nf][r] * alpha + bb;
                if (ACT == 1) v = fmaxf(v, 0.f);
                if (ACT == 2) v = 1.f / (1.f + __expf(-v));
                if (OUTMODE == 0) {
                    float o = v + (res ? res[(size_t)row * N + col] : 0.f);
                    ((float*)Cout)[(size_t)row * N + col] = o;
                } else if (OUTMODE == 1) {
                    ((ushort*)Cout)[(size_t)row * N + col] = f2bf(v);
                } else {
                    size_t orow = otrans ? trow(row) : (size_t)row;
                    size_t rrow = rtrans ? trow(row) : (size_t)row;
                    float o = v + (res ? res[rrow * N + col] : 0.f);
                    ((float*)Cout)[orow * N + col] = o;
                }
            }
        }
    }
}

// ------- q,k,v,g: A staged ONCE (32KB LDS), 4 weight GEMMs with direct-B, zero inner barriers -------
__global__ __launch_bounds__(256) void qkv4_gemm(
    const ushort* __restrict__ A, const ushort* __restrict__ wt4,
    ushort* __restrict__ qo, ushort* __restrict__ ko, ushort* __restrict__ vt,
    ushort* __restrict__ go, const float* __restrict__ bg,
    float scale_q, float scale_k)
{
    __shared__ ushort As[128*128];
    int t = threadIdx.x, l = t & 63, wv = t >> 6;
    int m0 = blockIdx.x << 7;
    int wm = (wv >> 1) << 6, wn = (wv & 1) << 6;
    int sr = t >> 1, scb = (t & 1) << 7;
    {
        const ushort* ap = A + (size_t)(m0 + sr) * CDIM + (scb >> 1);
        #pragma unroll
        for (int u = 0; u < 8; u++)
            *(int4*)((char*)As + swz256(sr, scb + (u << 4))) = *(const int4*)(ap + (u << 3));
    }
    __syncthreads();
    for (int comp = 0; comp < 4; comp++) {
        const ushort* W = wt4 + (size_t)comp * 16384;
        f32x4 acc[4][4] = {};
        #pragma unroll
        for (int ks = 0; ks < 4; ks++) {
            int kb = (ks << 6) + ((l >> 4) << 4);
            int kw = kb >> 1;
            bf16x8 a[4], b[4];
            #pragma unroll
            for (int x = 0; x < 4; x++) {
                a[x] = *(const bf16x8*)((char*)As + swz256(wm + (x << 4) + (l & 15), kb));
                b[x] = *(const bf16x8*)(W + (size_t)(wn + (x << 4) + (l & 15)) * CDIM + kw);
            }
            #pragma unroll
            for (int i = 0; i < 4; i++)
            #pragma unroll
            for (int j = 0; j < 4; j++)
                acc[i][j] = __builtin_amdgcn_mfma_f32_16x16x32_bf16(a[i], b[j], acc[i][j], 0, 0, 0);
        }
        #pragma unroll
        for (int mf = 0; mf < 4; mf++)
        #pragma unroll
        for (int nf = 0; nf < 4; nf++) {
            int col  = wn + (nf << 4) + (l & 15);
            int row0 = m0 + wm + (mf << 4) + ((l >> 4) << 2);
            if (comp == 0) {
                #pragma unroll
                for (int r = 0; r < 4; r++)
                    qo[(size_t)(row0 + r) * CDIM + col] = f2bf(acc[mf][nf][r] * scale_q);
            } else if (comp == 1) {
                #pragma unroll
                for (int r = 0; r < 4; r++)
                    ko[(size_t)(row0 + r) * CDIM + col] = f2bf(acc[mf][nf][r] * scale_k);
            } else if (comp == 2) {
                ushort4 pk;
                #pragma unroll
                for (int r = 0; r < 4; r++) ((ushort*)&pk)[r] = f2bf(acc[mf][nf][r]);
                int n = row0 / LDIM, j = row0 % LDIM;
                *(ushort4*)&vt[((size_t)(col >> 5) * 12288 + (size_t)n * 32 + (col & 31)) * 384 + j] = pk;
            } else {
                float bb = bg[col];
                #pragma unroll
                for (int r = 0; r < 4; r++) {
                    float v = acc[mf][nf][r] + bb;
                    go[(size_t)(row0 + r) * CDIM + col] = f2bf(1.f / (1.f + __expf(-v)));
                }
            }
        }
    }
}

// ------- tied scores, XCD-local decode: all 9 (ti,tj) blocks of one (h,cz) on one XCD -------
__global__ __launch_bounds__(256) void score128(const ushort* __restrict__ Q,
    const ushort* __restrict__ Kb, float* __restrict__ partial)
{
    __shared__ ushort As[128*128];
    __shared__ ushort Bs[128*128];
    int t = threadIdx.x, l = t & 63, wv = t >> 6;
    int id = blockIdx.x;                 // 288 blocks
    int xcd = id & 7, s9 = id >> 3;      // bid%8 ~ XCD (round-robin dispatch)
    int gl = s9 / 9, within = s9 % 9;    // 4 groups per XCD, 9 blocks per group
    int group = xcd * 4 + gl;            // 32 groups = (h, cz)
    int h = group >> 3, cz = group & 7;
    int ti = within / 3, tj = within % 3;
    int i0 = ti << 7, j0 = tj << 7;
    int wm = (wv >> 1) << 6, wn = (wv & 1) << 6;
    int sr = t >> 1, half = t & 1;
    f32x4 acc[4][4] = {};
    for (int it = 0; it < 12; it++) {
        if (it) __syncthreads();
        int nb = cz * 48 + (it << 2);
        #pragma unroll
        for (int e = 0; e < 2; e++) {
            int nq = (half << 1) + e;
            const ushort* qp = Q  + ((size_t)(nb + nq) * LDIM + i0 + sr) * CDIM + (h << 5);
            const ushort* kp = Kb + ((size_t)(nb + nq) * LDIM + j0 + sr) * CDIM + (h << 5);
            *(int4*)((char*)As + swz256(sr, (nq << 6) +  0)) = *(const int4*)qp;
            *(int4*)((char*)As + swz256(sr, (nq << 6) + 16)) = *(const int4*)(qp + 8);
            *(int4*)((char*)As + swz256(sr, (nq << 6) + 32)) = *(const int4*)(qp + 16);
            *(int4*)((char*)As + swz256(sr, (nq << 6) + 48)) = *(const int4*)(qp + 24);
            *(int4*)((char*)Bs + swz256(sr, (nq << 6) +  0)) = *(const int4*)kp;
            *(int4*)((char*)Bs + swz256(sr, (nq << 6) + 16)) = *(const int4*)(kp + 8);
            *(int4*)((char*)Bs + swz256(sr, (nq << 6) + 32)) = *(const int4*)(kp + 16);
            *(int4*)((char*)Bs + swz256(sr, (nq << 6) + 48)) = *(const int4*)(kp + 24);
        }
        __syncthreads();
        #pragma unroll
        for (int ks = 0; ks < 4; ks++) {
            int kb = (ks << 6) + ((l >> 4) << 4);
            bf16x8 a[4], b[4];
            #pragma unroll
            for (int x = 0; x < 4; x++) {
                a[x] = *(const bf16x8*)((char*)As + swz256(wm + (x << 4) + (l & 15), kb));
                b[x] = *(const bf16x8*)((char*)Bs + swz256(wn + (x << 4) + (l & 15), kb));
            }
            #pragma unroll
            for (int i = 0; i < 4; i++)
            #pragma unroll
            for (int j = 0; j < 4; j++)
                acc[i][j] = __builtin_amdgcn_mfma_f32_16x16x32_bf16(a[i], b[j], acc[i][j], 0, 0, 0);
        }
    }
    #pragma unroll
    for (int mf = 0; mf < 4; mf++)
    #pragma unroll
    for (int nf = 0; nf < 4; nf++) {
        int j = j0 + wn + (nf << 4) + (l & 15);
        int i = i0 + wm + (mf << 4) + ((l >> 4) << 2);
        #pragma unroll
        for (int r = 0; r < 4; r++)
            partial[((size_t)(cz*HN + h)*LDIM + i + r)*LDIM + j] = acc[mf][nf][r];
    }
}

// ---------------- softmax over j (chunk reduce + bias) -> bf16 ----------------
__global__ __launch_bounds__(64) void softmax_kernel(
    const float* __restrict__ partial, const float* __restrict__ battn, ushort* __restrict__ attn)
{
    int hi = blockIdx.x;
    int l = threadIdx.x;
    float s[6];
    #pragma unroll
    for (int u = 0; u < 6; u++) {
        size_t idx = (size_t)hi * LDIM + l + (u << 6);
        float v = battn[idx];
        #pragma unroll
        for (int c = 0; c < NCHUNK; c++) v += partial[(size_t)c * HN * LL + idx];
        s[u] = v;
    }
    float m = s[0];
    #pragma unroll
    for (int u = 1; u < 6; u++) m = fmaxf(m, s[u]);
    #pragma unroll
    for (int off = 32; off; off >>= 1) m = fmaxf(m, __shfl_xor(m, off, 64));
    float sum = 0.f;
    #pragma unroll
    for (int u = 0; u < 6; u++) { s[u] = __expf(s[u] - m); sum += s[u]; }
    #pragma unroll
    for (int off = 32; off; off >>= 1) sum += __shfl_xor(sum, off, 64);
    float inv = 1.f / sum;
    #pragma unroll
    for (int u = 0; u < 6; u++) attn[(size_t)hi * LDIM + l + (u << 6)] = f2bf(s[u] * inv);
}

// ------- PV per-head GEMM (BK=64): pvout[(n,i),h*32+d] -------
__global__ __launch_bounds__(256) void pvg_gemm(const ushort* __restrict__ attn,
    const ushort* __restrict__ vt, ushort* __restrict__ pvout)
{
    __shared__ ushort As[128*64];
    __shared__ ushort Ws[128*64];
    int t = threadIdx.x, l = t & 63, wv = t >> 6;
    int n0 = blockIdx.x << 7;
    int i0 = blockIdx.y << 7;
    int h  = blockIdx.z;
    const ushort* abase = attn + (size_t)h * LL;
    const ushort* bbase = vt + (size_t)h * VTPLANE;
    int wm = (wv >> 1) << 6, wn = (wv & 1) << 6;
    int sr = t >> 1, sh = (t & 1) << 5;
    f32x4 acc[4][4] = {};
    for (int k0 = 0; k0 < LDIM; k0 += 64) {
        if (k0) __syncthreads();
        {
            const ushort* ap = abase + (size_t)(i0 + sr) * LDIM + k0 + sh;
            const ushort* bp = bbase + (size_t)(n0 + sr) * LDIM + k0 + sh;
            #pragma unroll
            for (int u = 0; u < 4; u++) {
                *(int4*)((char*)As + swz128(sr, (sh << 1) + (u << 4))) = *(const int4*)(ap + (u << 3));
                *(int4*)((char*)Ws + swz128(sr, (sh << 1) + (u << 4))) = *(const int4*)(bp + (u << 3));
            }
        }
        __syncthreads();
        #pragma unroll
        for (int ks = 0; ks < 2; ks++) {
            int kb = (ks << 6) + ((l >> 4) << 4);
            bf16x8 a[4], b[4];
            #pragma unroll
            for (int x = 0; x < 4; x++) {
                a[x] = *(const bf16x8*)((char*)As + swz128(wm + (x << 4) + (l & 15), kb));
                b[x] = *(const bf16x8*)((char*)Ws + swz128(wn + (x << 4) + (l & 15), kb));
            }
            #pragma unroll
            for (int i = 0; i < 4; i++)
            #pragma unroll
            for (int j = 0; j < 4; j++)
                acc[i][j] = __builtin_amdgcn_mfma_f32_16x16x32_bf16(a[i], b[j], acc[i][j], 0, 0, 0);
        }
    }
    #pragma unroll
    for (int mf = 0; mf < 4; mf++)
    #pragma unroll
    for (int nf = 0; nf < 4; nf++) {
        int col  = n0 + wn + (nf << 4) + (l & 15);
        int row0 = i0 + wm + (mf << 4) + ((l >> 4) << 2);
        int n = col >> 5, d = col & 31;
        #pragma unroll
        for (int r = 0; r < 4; r++) {
            int i = row0 + r;
            pvout[((size_t)n * LDIM + i) * CDIM + (h << 5) + d] = f2bf(acc[mf][nf][r]);
        }
    }
}

extern "C" void kernel_launch(void* const* d_in, const int* in_sizes, int n_in,
                              void* d_out, int out_size, void* d_ws, size_t ws_size,
                              hipStream_t stream)
{
    const float* pair     = (const float*)d_in[0];
    const float* rbf_feat = (const float*)d_in[1];
    const float* emb_b    = (const float*)d_in[3];
    const float* proj_b   = (const float*)d_in[5];
    const float* ff_ln_w  = (const float*)d_in[30];
    const float* ff_ln_b  = (const float*)d_in[31];
    const float* ff_b1    = (const float*)d_in[33];
    const float* ff_b2    = (const float*)d_in[35];
    float* out = (float*)d_out;

    ushort* R0 = (ushort*)d_ws;
    ushort* R1 = R0 + (size_t)LL*CDIM;
    ushort* R2 = R1 + (size_t)LL*CDIM;
    ushort* R3 = R2 + (size_t)LL*CDIM;
    float*  partialb = (float*)(R3 + (size_t)LL*CDIM);
    float*  battn_r  = partialb + (size_t)NCHUNK*HN*LL;
    float*  battn_c  = battn_r  + (size_t)HN*LL;
    ushort* attn_bf  = (ushort*)(battn_c + (size_t)HN*LL);
    ushort* wt       = attn_bf + (size_t)HN*LL;

    size_t need_bytes = (size_t)4*LL*CDIM*2 + ((size_t)NCHUNK*HN*LL + 2*(size_t)HN*LL)*4
                      + (size_t)HN*LL*2 + (size_t)262144*2;
    if (ws_size < need_bytes) return;

    const size_t WS = 16384;
    ushort* wt_emb  = wt;
    ushort* wt_proj = wt + WS;
    ushort* wt_ff1  = wt + 12*WS;
    ushort* wt_ff2  = wt + 12*WS + 32768;

    const float SCALE = 0.17677669529663687f;  // 32^-0.5

    wprep_kernel<<<dim3(128, 14), 256, 0, stream>>>(wt,
        (const float*)d_in[2], (const float*)d_in[4],
        (const float*)d_in[10], (const float*)d_in[11], (const float*)d_in[12],
        (const float*)d_in[14], (const float*)d_in[16],
        (const float*)d_in[22], (const float*)d_in[23], (const float*)d_in[24],
        (const float*)d_in[26], (const float*)d_in[28],
        (const float*)d_in[32], (const float*)d_in[34]);

    // rbf = relu(rbf_feat@emb+eb)@proj+pb : hidden bf16 -> R3; rbf fp32 spans R0+R1
    dgemm128<1,0,1,0><<<dim3(1,1152), 256, 0, stream>>>(rbf_feat, wt_emb, emb_b, nullptr, nullptr, R3,
        nullptr, nullptr, nullptr, 128, 128, 36, 1.f, 0, 0);
    dgemm128<0,1,0,0><<<dim3(1,1152), 256, 0, stream>>>(R3, wt_proj, proj_b, nullptr, nullptr, (float*)R0,
        nullptr, nullptr, nullptr, 128, 128, 128, 1.f, 0, 0);
    battn_kernel<<<LL/4, 256, 0, stream>>>((const float*)R0, battn_r,
        (const float*)d_in[8],  (const float*)d_in[9],  (const float*)d_in[13], 1);
    battn_kernel<<<LL/4, 256, 0, stream>>>((const float*)R0, battn_c,
        (const float*)d_in[20], (const float*)d_in[21], (const float*)d_in[25], 0);

    // initial row-pass xln (transposed frame) -> R3
    lnpack_kernel<<<LL/4, 256, 0, stream>>>(pair, R3, (const float*)d_in[6], (const float*)d_in[7], 1);

    ushort* XLN = R3;
    for (int pass = 0; pass < 2; pass++) {
        const float* const* wp = (const float* const*)(d_in + (pass ? 18 : 6));
        int trans = pass ? 0 : 1;
        const float* P = pass ? (const float*)out : pair;
        const float* battnb = pass ? battn_c : battn_r;
        int ws0 = pass ? 7 : 2;   // wq slot; wk,wv,wg,wo follow
        const float* nlw = pass ? ff_ln_w : (const float*)d_in[18];
        const float* nlb = pass ? ff_ln_b : (const float*)d_in[19];
        ushort* Qb   = R0;
        ushort* Kb2  = pass ? R3 : R1;
        ushort* VTb  = R2;
        ushort* PVb  = R0;
        ushort* XLNn = pass ? R3 : R1;
        // q,k,v,g off one staged A (g overwrites XLN in place — blocks only touch own rows)
        qkv4_gemm<<<1152, 256, 0, stream>>>(XLN, wt + ws0*WS, Qb, Kb2, VTb, XLN, wp[9], SCALE, 1.f/LDIM);
        score128<<<288, 256, 0, stream>>>(Qb, Kb2, partialb);
        softmax_kernel<<<HN*LDIM, 64, 0, stream>>>(partialb, battnb, attn_bf);
        pvg_gemm<<<dim3(96, 3, 4), 256, 0, stream>>>(attn_bf, VTb, PVb);
        // pair_out = residual + (g .* pv)@wo + bo ; fused LN -> next xln
        dgemm128<0,2,3,1><<<dim3(1,1152), 256, 0, stream>>>(PVb, wt + (ws0+4)*WS, wp[11], XLN, P, out,
            nlw, nlb, XLNn, 128, 128, 128, 1.f, trans, trans);
        XLN = XLNn;
    }

    // FFN: out += relu(xln@w1+b1)@w2+b2  (h1 bf16 [LL][256] spans R0+R1)
    dgemm128<1,1,1,0><<<dim3(2,1152), 256, 0, stream>>>(XLN, wt_ff1, ff_b1, nullptr, nullptr, R0,
        nullptr, nullptr, nullptr, 256, 128, 128, 1.f, 0, 0);
    dgemm128<0,1,0,0><<<dim3(1,1152), 256, 0, stream>>>(R0, wt_ff2, ff_b2, nullptr, out, out,
        nullptr, nullptr, nullptr, 128, 256, 256, 1.f, 0, 0);
}

// Round 12
// 862.679 us; speedup vs baseline: 1.0778x; 1.0778x over previous
//
#include <hip/hip_runtime.h>
#include <hip/hip_bf16.h>
#include <math.h>

#define LDIM 384
#define CDIM 128
#define HN 4
#define LL (LDIM*LDIM)
#define NCHUNK 8
#define VTPLANE ((size_t)12288*384)

typedef __attribute__((ext_vector_type(8))) short bf16x8;
typedef __attribute__((ext_vector_type(4))) float f32x4;

__device__ __forceinline__ ushort f2bf(float x) {
    union { __hip_bfloat16 h; ushort u; } cv;
    cv.h = __float2bfloat16(x);
    return cv.u;
}
__device__ __forceinline__ float bf2f(ushort u) {
    union { unsigned int i; float f; } cv; cv.i = ((unsigned int)u) << 16; return cv.f;
}
__device__ __forceinline__ int swz256(int row, int cb) { return (row * 256 + cb) ^ ((row & 7) << 4); }
__device__ __forceinline__ int swz128(int row, int cb) { return (row * 128 + cb) ^ ((row & 7) << 4); }
__device__ __forceinline__ size_t trow(int row) { return (size_t)(row % LDIM) * LDIM + row / LDIM; }

// ---------------- weight prep: fp32 [K][N] -> bf16 [N][KP] (zero-padded K) ----------------
__global__ __launch_bounds__(256) void wprep_kernel(ushort* __restrict__ wt,
    const float* emb_w, const float* proj_w,
    const float* rwq, const float* rwk, const float* rwv, const float* rwg, const float* rwo,
    const float* cwq, const float* cwk, const float* cwv, const float* cwg, const float* cwo,
    const float* ffw1, const float* ffw2)
{
    int y = blockIdx.y;
    const float* src; int N, K, KP; size_t off;
    switch (y) {
        case 0:  src = emb_w;  N = 128; K = 36;  KP = 128; off = 0;         break;
        case 1:  src = proj_w; N = 128; K = 128; KP = 128; off = 16384;     break;
        case 2:  src = rwq;    N = 128; K = 128; KP = 128; off = 2*16384;   break;
        case 3:  src = rwk;    N = 128; K = 128; KP = 128; off = 3*16384;   break;
        case 4:  src = rwv;    N = 128; K = 128; KP = 128; off = 4*16384;   break;
        case 5:  src = rwg;    N = 128; K = 128; KP = 128; off = 5*16384;   break;
        case 6:  src = rwo;    N = 128; K = 128; KP = 128; off = 6*16384;   break;
        case 7:  src = cwq;    N = 128; K = 128; KP = 128; off = 7*16384;   break;
        case 8:  src = cwk;    N = 128; K = 128; KP = 128; off = 8*16384;   break;
        case 9:  src = cwv;    N = 128; K = 128; KP = 128; off = 9*16384;   break;
        case 10: src = cwg;    N = 128; K = 128; KP = 128; off = 10*16384;  break;
        case 11: src = cwo;    N = 128; K = 128; KP = 128; off = 11*16384;  break;
        case 12: src = ffw1;   N = 256; K = 128; KP = 128; off = 12*16384;  break;
        default: src = ffw2;   N = 128; K = 256; KP = 256; off = 12*16384 + 32768; break;
    }
    int e = blockIdx.x * 256 + threadIdx.x;
    if (e >= N * KP) return;
    int nn = e / KP, kp = e - nn * KP;
    float v = (kp < K) ? src[(size_t)kp * N + nn] : 0.f;
    wt[off + e] = f2bf(v);
}

// ------- LN + bf16 pack: coalesced read of src row p, write to dst row trans(p) -------
__global__ __launch_bounds__(256) void lnpack_kernel(const float* __restrict__ src,
    ushort* __restrict__ dst, const float* __restrict__ w, const float* __restrict__ b, int trans)
{
    int p = (blockIdx.x << 2) + (threadIdx.x >> 6);
    int lane = threadIdx.x & 63;
    float2 v = *(const float2*)(src + (size_t)p * CDIM + (lane << 1));
    float s  = v.x + v.y;
    float ss = v.x*v.x + v.y*v.y;
    #pragma unroll
    for (int off = 32; off; off >>= 1) { s += __shfl_xor(s, off, 64); ss += __shfl_xor(ss, off, 64); }
    float mean = s * (1.0f/CDIM);
    float var  = ss * (1.0f/CDIM) - mean*mean;
    float rstd = rsqrtf(var + 1e-5f);
    int q = trans ? ((p % LDIM) * LDIM + p / LDIM) : p;
    ushort2 o;
    o.x = f2bf((v.x - mean) * rstd * w[lane<<1]     + b[lane<<1]);
    o.y = f2bf((v.y - mean) * rstd * w[(lane<<1)+1] + b[(lane<<1)+1]);
    *(ushort2*)(dst + (size_t)q * CDIM + (lane << 1)) = o;
}

// ------- dual bias-attention: read rbf row p=(a,b) ONCE, shared LN stats, write BOTH frames -------
__global__ __launch_bounds__(256) void battn2_kernel(const float* __restrict__ rbf,
    float* __restrict__ battn_r, float* __restrict__ battn_c,
    const float* __restrict__ rlnw, const float* __restrict__ rlnb, const float* __restrict__ rwb,
    const float* __restrict__ clnw, const float* __restrict__ clnb, const float* __restrict__ cwb)
{
    int p = (blockIdx.x << 2) + (threadIdx.x >> 6);
    int lane = threadIdx.x & 63;
    int a = p / LDIM, b2 = p % LDIM;
    float2 v = *(const float2*)(rbf + (size_t)p * CDIM + (lane << 1));
    float s = v.x + v.y, ss = v.x*v.x + v.y*v.y;
    #pragma unroll
    for (int off = 32; off; off >>= 1) { s += __shfl_xor(s, off, 64); ss += __shfl_xor(ss, off, 64); }
    float mean = s*(1.f/CDIM), var = ss*(1.f/CDIM) - mean*mean, rstd = rsqrtf(var + 1e-5f);
    float c0x = (v.x - mean) * rstd, c1x = (v.y - mean) * rstd;
    int e0 = lane << 1, e1 = e0 + 1;
    float xr0 = c0x * rlnw[e0] + rlnb[e0], xr1 = c1x * rlnw[e1] + rlnb[e1];
    float xc0 = c0x * clnw[e0] + clnb[e0], xc1 = c1x * clnw[e1] + clnb[e1];
    int q0 = e0 * HN, q1 = e1 * HN;
    float r0 = xr0*rwb[q0+0] + xr1*rwb[q1+0];
    float r1 = xr0*rwb[q0+1] + xr1*rwb[q1+1];
    float r2 = xr0*rwb[q0+2] + xr1*rwb[q1+2];
    float r3 = xr0*rwb[q0+3] + xr1*rwb[q1+3];
    float c0 = xc0*cwb[q0+0] + xc1*cwb[q1+0];
    float c1 = xc0*cwb[q0+1] + xc1*cwb[q1+1];
    float c2 = xc0*cwb[q0+2] + xc1*cwb[q1+2];
    float c3 = xc0*cwb[q0+3] + xc1*cwb[q1+3];
    #pragma unroll
    for (int off = 32; off; off >>= 1) {
        r0 += __shfl_xor(r0, off, 64); r1 += __shfl_xor(r1, off, 64);
        r2 += __shfl_xor(r2, off, 64); r3 += __shfl_xor(r3, off, 64);
        c0 += __shfl_xor(c0, off, 64); c1 += __shfl_xor(c1, off, 64);
        c2 += __shfl_xor(c2, off, 64); c3 += __shfl_xor(c3, off, 64);
    }
    if (lane == 0) {
        // row-pass frame is transposed: battn_r[h][i=b2][j=a]; col-pass natural: battn_c[h][i=a][j=b2]
        battn_r[((size_t)0*LDIM + b2)*LDIM + a] = r0;
        battn_r[((size_t)1*LDIM + b2)*LDIM + a] = r1;
        battn_r[((size_t)2*LDIM + b2)*LDIM + a] = r2;
        battn_r[((size_t)3*LDIM + b2)*LDIM + a] = r3;
        battn_c[((size_t)0*LDIM + a)*LDIM + b2] = c0;
        battn_c[((size_t)1*LDIM + a)*LDIM + b2] = c1;
        battn_c[((size_t)2*LDIM + a)*LDIM + b2] = c2;
        battn_c[((size_t)3*LDIM + a)*LDIM + b2] = c3;
    }
}

// ------- BK=64 128x128-tile MFMA GEMM (round-7 verified config). -------
// AMODE: 0 fp32, 1 bf16, 2 bf16 gated. OUTMODE: 0 fp32 (+res), 1 bf16, 3 fp32 w/ rtrans/otrans.
// LNOUT: fuse LN over 128 out channels (N=128, grid.x=1, OUTMODE3): writes out fp32 + xln bf16.
template<int ACT, int AMODE, int OUTMODE, int LNOUT>
__global__ __launch_bounds__(256) void mgemm64(
    const void* __restrict__ Ain, const ushort* __restrict__ Wt,
    const float* __restrict__ bias, const ushort* __restrict__ gmul,
    const float* __restrict__ res, void* __restrict__ Cout,
    const float* __restrict__ lnw2, const float* __restrict__ lnb2, ushort* __restrict__ xln,
    int N, int KP, int lda, float alpha, int rtrans, int otrans)
{
    __shared__ ushort As[128*64];
    __shared__ ushort Ws[128*64];
    int t = threadIdx.x, l = t & 63, wv = t >> 6;
    int m0 = blockIdx.y << 7, n0 = blockIdx.x << 7;
    int wm = (wv >> 1) << 6, wn = (wv & 1) << 6;
    int sr = t >> 1;            // staging row
    int sh = (t & 1) << 5;      // k offset (shorts)
    f32x4 acc[4][4] = {};
    for (int k0 = 0; k0 < KP; k0 += 64) {
        if (k0) __syncthreads();
        if (AMODE == 1) {
            const ushort* ap = (const ushort*)Ain + (size_t)(m0 + sr) * lda + k0 + sh;
            #pragma unroll
            for (int u = 0; u < 4; u++)
                *(int4*)((char*)As + swz128(sr, (sh << 1) + (u << 4))) = *(const int4*)(ap + (u << 3));
        } else if (AMODE == 2) {
            const ushort* ap = (const ushort*)Ain + (size_t)(m0 + sr) * lda + k0 + sh;
            const ushort* gp = gmul + (size_t)(m0 + sr) * lda + k0 + sh;
            #pragma unroll
            for (int u = 0; u < 4; u++) {
                int4 av = *(const int4*)(ap + (u << 3));
                int4 gv = *(const int4*)(gp + (u << 3));
                ushort* au = (ushort*)&av; ushort* gu = (ushort*)&gv;
                short v8[8];
                #pragma unroll
                for (int e = 0; e < 8; e++) v8[e] = (short)f2bf(bf2f(au[e]) * bf2f(gu[e]));
                *(int4*)((char*)As + swz128(sr, (sh << 1) + (u << 4))) = *(int4*)v8;
            }
        } else {
            const float* ap = (const float*)Ain + (size_t)(m0 + sr) * lda;
            #pragma unroll
            for (int u = 0; u < 4; u++) {
                short v8[8];
                #pragma unroll
                for (int e = 0; e < 8; e++) {
                    int c = k0 + sh + (u << 3) + e;
                    v8[e] = (short)f2bf((c < lda) ? ap[c] : 0.f);
                }
                *(int4*)((char*)As + swz128(sr, (sh << 1) + (u << 4))) = *(int4*)v8;
            }
        }
        {
            const ushort* wp2 = Wt + (size_t)(n0 + sr) * KP + k0 + sh;
            #pragma unroll
            for (int u = 0; u < 4; u++)
                *(int4*)((char*)Ws + swz128(sr, (sh << 1) + (u << 4))) = *(const int4*)(wp2 + (u << 3));
        }
        __syncthreads();
        #pragma unroll
        for (int ks = 0; ks < 2; ks++) {
            int kb = (ks << 6) + ((l >> 4) << 4);
            bf16x8 a[4], b[4];
            #pragma unroll
            for (int x = 0; x < 4; x++) {
                a[x] = *(const bf16x8*)((char*)As + swz128(wm + (x << 4) + (l & 15), kb));
                b[x] = *(const bf16x8*)((char*)Ws + swz128(wn + (x << 4) + (l & 15), kb));
            }
            #pragma unroll
            for (int i = 0; i < 4; i++)
            #pragma unroll
            for (int j = 0; j < 4; j++)
                acc[i][j] = __builtin_amdgcn_mfma_f32_16x16x32_bf16(a[i], b[j], acc[i][j], 0, 0, 0);
        }
    }
    if (LNOUT) {
        #pragma unroll
        for (int mf = 0; mf < 4; mf++)
        #pragma unroll
        for (int nf = 0; nf < 4; nf++) {
            int col  = wn + (nf << 4) + (l & 15);
            int row0 = m0 + wm + (mf << 4) + ((l >> 4) << 2);
            float bb = bias ? bias[col] : 0.f;
            #pragma unroll
            for (int r = 0; r < 4; r++) {
                int row = row0 + r;
                size_t rrow = rtrans ? trow(row) : (size_t)row;
                acc[mf][nf][r] = acc[mf][nf][r] * alpha + bb + (res ? res[rrow * CDIM + col] : 0.f);
            }
        }
        float ps[4][4], pq[4][4];
        #pragma unroll
        for (int mf = 0; mf < 4; mf++)
        #pragma unroll
        for (int r = 0; r < 4; r++) {
            float s = 0.f, q = 0.f;
            #pragma unroll
            for (int nf = 0; nf < 4; nf++) { float v = acc[mf][nf][r]; s += v; q += v * v; }
            ps[mf][r] = s; pq[mf][r] = q;
        }
        #pragma unroll
        for (int off = 1; off < 16; off <<= 1)
        #pragma unroll
        for (int mf = 0; mf < 4; mf++)
        #pragma unroll
        for (int r = 0; r < 4; r++) {
            ps[mf][r] += __shfl_xor(ps[mf][r], off, 64);
            pq[mf][r] += __shfl_xor(pq[mf][r], off, 64);
        }
        __syncthreads();
        float* lnbuf = (float*)As;       // [2][128][2]
        if ((l & 15) == 0) {
            #pragma unroll
            for (int mf = 0; mf < 4; mf++)
            #pragma unroll
            for (int r = 0; r < 4; r++) {
                int rl = wm + (mf << 4) + ((l >> 4) << 2) + r;
                lnbuf[(((wv & 1) << 7) + rl) * 2 + 0] = ps[mf][r];
                lnbuf[(((wv & 1) << 7) + rl) * 2 + 1] = pq[mf][r];
            }
        }
        __syncthreads();
        #pragma unroll
        for (int mf = 0; mf < 4; mf++)
        #pragma unroll
        for (int nf = 0; nf < 4; nf++) {
            int col  = wn + (nf << 4) + (l & 15);
            int row0 = m0 + wm + (mf << 4) + ((l >> 4) << 2);
            float lw = lnw2[col], lb = lnb2[col];
            #pragma unroll
            for (int r = 0; r < 4; r++) {
                int row = row0 + r;
                int rl  = wm + (mf << 4) + ((l >> 4) << 2) + r;
                float s  = lnbuf[rl * 2 + 0] + lnbuf[(256 + rl * 2) + 0];
                float q  = lnbuf[rl * 2 + 1] + lnbuf[(256 + rl * 2) + 1];
                float mean = s * (1.f/CDIM);
                float var  = q * (1.f/CDIM) - mean * mean;
                float rstd = rsqrtf(var + 1e-5f);
                float o = acc[mf][nf][r];
                size_t orow = otrans ? trow(row) : (size_t)row;
                ((float*)Cout)[orow * CDIM + col] = o;
                xln[orow * CDIM + col] = f2bf((o - mean) * rstd * lw + lb);
            }
        }
    } else {
        #pragma unroll
        for (int mf = 0; mf < 4; mf++)
        #pragma unroll
        for (int nf = 0; nf < 4; nf++) {
            int col  = n0 + wn + (nf << 4) + (l & 15);
            int row0 = m0 + wm + (mf << 4) + ((l >> 4) << 2);
            float bb = bias ? bias[col] : 0.f;
            #pragma unroll
            for (int r = 0; r < 4; r++) {
                int row = row0 + r;
                float v = acc[mf][nf][r] * alpha + bb;
                if (ACT == 1) v = fmaxf(v, 0.f);
                if (ACT == 2) v = 1.f / (1.f + __expf(-v));
                if (OUTMODE == 0) {
                    float o = v + (res ? res[(size_t)row * N + col] : 0.f);
                    ((float*)Cout)[(size_t)row * N + col] = o;
                } else if (OUTMODE == 1) {
                    ((ushort*)Cout)[(size_t)row * N + col] = f2bf(v);
                } else {
                    size_t orow = otrans ? trow(row) : (size_t)row;
                    size_t rrow = rtrans ? trow(row) : (size_t)row;
                    float o = v + (res ? res[rrow * N + col] : 0.f);
                    ((float*)Cout)[orow * N + col] = o;
                }
            }
        }
    }
}

// ------- q,k,v,g in one kernel: A staged ONCE; W staged per comp (verified r10 structure) -------
__global__ __launch_bounds__(256) void qkv4_gemm(
    const ushort* __restrict__ A, const ushort* __restrict__ wt4,
    ushort* __restrict__ qo, ushort* __restrict__ ko, ushort* __restrict__ vt,
    ushort* __restrict__ go, const float* __restrict__ bg,
    float scale_q, float scale_k)
{
    __shared__ ushort As[128*128];
    __shared__ ushort Ws[128*128];
    int t = threadIdx.x, l = t & 63, wv = t >> 6;
    int m0 = blockIdx.x << 7;
    int wm = (wv >> 1) << 6, wn = (wv & 1) << 6;
    int sr = t >> 1, scb = (t & 1) << 7;
    {
        const ushort* ap = A + (size_t)(m0 + sr) * CDIM + (scb >> 1);
        #pragma unroll
        for (int u = 0; u < 8; u++)
            *(int4*)((char*)As + swz256(sr, scb + (u << 4))) = *(const int4*)(ap + (u << 3));
    }
    for (int comp = 0; comp < 4; comp++) {
        if (comp) __syncthreads();
        const ushort* wp2 = wt4 + (size_t)comp * 16384 + (size_t)sr * CDIM + (scb >> 1);
        #pragma unroll
        for (int u = 0; u < 8; u++)
            *(int4*)((char*)Ws + swz256(sr, scb + (u << 4))) = *(const int4*)(wp2 + (u << 3));
        __syncthreads();
        f32x4 acc[4][4] = {};
        #pragma unroll
        for (int ks = 0; ks < 4; ks++) {
            int kb = (ks << 6) + ((l >> 4) << 4);
            bf16x8 a[4], b[4];
            #pragma unroll
            for (int x = 0; x < 4; x++) {
                a[x] = *(const bf16x8*)((char*)As + swz256(wm + (x << 4) + (l & 15), kb));
                b[x] = *(const bf16x8*)((char*)Ws + swz256(wn + (x << 4) + (l & 15), kb));
            }
            #pragma unroll
            for (int i = 0; i < 4; i++)
            #pragma unroll
            for (int j = 0; j < 4; j++)
                acc[i][j] = __builtin_amdgcn_mfma_f32_16x16x32_bf16(a[i], b[j], acc[i][j], 0, 0, 0);
        }
        #pragma unroll
        for (int mf = 0; mf < 4; mf++)
        #pragma unroll
        for (int nf = 0; nf < 4; nf++) {
            int col  = wn + (nf << 4) + (l & 15);
            int row0 = m0 + wm + (mf << 4) + ((l >> 4) << 2);
            if (comp == 0) {
                #pragma unroll
                for (int r = 0; r < 4; r++)
                    qo[(size_t)(row0 + r) * CDIM + col] = f2bf(acc[mf][nf][r] * scale_q);
            } else if (comp == 1) {
                #pragma unroll
                for (int r = 0; r < 4; r++)
                    ko[(size_t)(row0 + r) * CDIM + col] = f2bf(acc[mf][nf][r] * scale_k);
            } else if (comp == 2) {
                ushort4 pk;
                #pragma unroll
                for (int r = 0; r < 4; r++) ((ushort*)&pk)[r] = f2bf(acc[mf][nf][r]);
                int n = row0 / LDIM, j = row0 % LDIM;
                *(ushort4*)&vt[((size_t)(col >> 5) * 12288 + (size_t)n * 32 + (col & 31)) * 384 + j] = pk;
            } else {
                float bb = bg[col];
                #pragma unroll
                for (int r = 0; r < 4; r++) {
                    float v = acc[mf][nf][r] + bb;
                    go[(size_t)(row0 + r) * CDIM + col] = f2bf(1.f / (1.f + __expf(-v)));
                }
            }
        }
    }
}

// ------- tied scores (verified round-7 3D grid): partial[cz,h,i,j] -------
__global__ __launch_bounds__(256) void score128(const ushort* __restrict__ Q,
    const ushort* __restrict__ Kb, float* __restrict__ partial)
{
    __shared__ ushort As[128*128];
    __shared__ ushort Bs[128*128];
    int t = threadIdx.x, l = t & 63, wv = t >> 6;
    int ti = blockIdx.x / 3, tj = blockIdx.x % 3;
    int h = blockIdx.y, cz = blockIdx.z;
    int i0 = ti << 7, j0 = tj << 7;
    int wm = (wv >> 1) << 6, wn = (wv & 1) << 6;
    int sr = t >> 1, half = t & 1;
    f32x4 acc[4][4] = {};
    for (int it = 0; it < 12; it++) {
        if (it) __syncthreads();
        int nb = cz * 48 + (it << 2);
        #pragma unroll
        for (int e = 0; e < 2; e++) {
            int nq = (half << 1) + e;
            const ushort* qp = Q  + ((size_t)(nb + nq) * LDIM + i0 + sr) * CDIM + (h << 5);
            const ushort* kp = Kb + ((size_t)(nb + nq) * LDIM + j0 + sr) * CDIM + (h << 5);
            *(int4*)((char*)As + swz256(sr, (nq << 6) +  0)) = *(const int4*)qp;
            *(int4*)((char*)As + swz256(sr, (nq << 6) + 16)) = *(const int4*)(qp + 8);
            *(int4*)((char*)As + swz256(sr, (nq << 6) + 32)) = *(const int4*)(qp + 16);
            *(int4*)((char*)As + swz256(sr, (nq << 6) + 48)) = *(const int4*)(qp + 24);
            *(int4*)((char*)Bs + swz256(sr, (nq << 6) +  0)) = *(const int4*)kp;
            *(int4*)((char*)Bs + swz256(sr, (nq << 6) + 16)) = *(const int4*)(kp + 8);
            *(int4*)((char*)Bs + swz256(sr, (nq << 6) + 32)) = *(const int4*)(kp + 16);
            *(int4*)((char*)Bs + swz256(sr, (nq << 6) + 48)) = *(const int4*)(kp + 24);
        }
        __syncthreads();
        #pragma unroll
        for (int ks = 0; ks < 4; ks++) {
            int kb = (ks << 6) + ((l >> 4) << 4);
            bf16x8 a[4], b[4];
            #pragma unroll
            for (int x = 0; x < 4; x++) {
                a[x] = *(const bf16x8*)((char*)As + swz256(wm + (x << 4) + (l & 15), kb));
                b[x] = *(const bf16x8*)((char*)Bs + swz256(wn + (x << 4) + (l & 15), kb));
            }
            #pragma unroll
            for (int i = 0; i < 4; i++)
            #pragma unroll
            for (int j = 0; j < 4; j++)
                acc[i][j] = __builtin_amdgcn_mfma_f32_16x16x32_bf16(a[i], b[j], acc[i][j], 0, 0, 0);
        }
    }
    #pragma unroll
    for (int mf = 0; mf < 4; mf++)
    #pragma unroll
    for (int nf = 0; nf < 4; nf++) {
        int j = j0 + wn + (nf << 4) + (l & 15);
        int i = i0 + wm + (mf << 4) + ((l >> 4) << 2);
        #pragma unroll
        for (int r = 0; r < 4; r++)
            partial[((size_t)(cz*HN + h)*LDIM + i + r)*LDIM + j] = acc[mf][nf][r];
    }
}

// ---------------- softmax over j (chunk reduce + bias) -> bf16 ----------------
__global__ __launch_bounds__(64) void softmax_kernel(
    const float* __restrict__ partial, const float* __restrict__ battn, ushort* __restrict__ attn)
{
    int hi = blockIdx.x;
    int l = threadIdx.x;
    float s[6];
    #pragma unroll
    for (int u = 0; u < 6; u++) {
        size_t idx = (size_t)hi * LDIM + l + (u << 6);
        float v = battn[idx];
        #pragma unroll
        for (int c = 0; c < NCHUNK; c++) v += partial[(size_t)c * HN * LL + idx];
        s[u] = v;
    }
    float m = s[0];
    #pragma unroll
    for (int u = 1; u < 6; u++) m = fmaxf(m, s[u]);
    #pragma unroll
    for (int off = 32; off; off >>= 1) m = fmaxf(m, __shfl_xor(m, off, 64));
    float sum = 0.f;
    #pragma unroll
    for (int u = 0; u < 6; u++) { s[u] = __expf(s[u] - m); sum += s[u]; }
    #pragma unroll
    for (int off = 32; off; off >>= 1) sum += __shfl_xor(sum, off, 64);
    float inv = 1.f / sum;
    #pragma unroll
    for (int u = 0; u < 6; u++) attn[(size_t)hi * LDIM + l + (u << 6)] = f2bf(s[u] * inv);
}

// ------- PV per-head GEMM (BK=64): pvout[(n,i),h*32+d] -------
__global__ __launch_bounds__(256) void pvg_gemm(const ushort* __restrict__ attn,
    const ushort* __restrict__ vt, ushort* __restrict__ pvout)
{
    __shared__ ushort As[128*64];
    __shared__ ushort Ws[128*64];
    int t = threadIdx.x, l = t & 63, wv = t >> 6;
    int n0 = blockIdx.x << 7;
    int i0 = blockIdx.y << 7;
    int h  = blockIdx.z;
    const ushort* abase = attn + (size_t)h * LL;
    const ushort* bbase = vt + (size_t)h * VTPLANE;
    int wm = (wv >> 1) << 6, wn = (wv & 1) << 6;
    int sr = t >> 1, sh = (t & 1) << 5;
    f32x4 acc[4][4] = {};
    for (int k0 = 0; k0 < LDIM; k0 += 64) {
        if (k0) __syncthreads();
        {
            const ushort* ap = abase + (size_t)(i0 + sr) * LDIM + k0 + sh;
            const ushort* bp = bbase + (size_t)(n0 + sr) * LDIM + k0 + sh;
            #pragma unroll
            for (int u = 0; u < 4; u++) {
                *(int4*)((char*)As + swz128(sr, (sh << 1) + (u << 4))) = *(const int4*)(ap + (u << 3));
                *(int4*)((char*)Ws + swz128(sr, (sh << 1) + (u << 4))) = *(const int4*)(bp + (u << 3));
            }
        }
        __syncthreads();
        #pragma unroll
        for (int ks = 0; ks < 2; ks++) {
            int kb = (ks << 6) + ((l >> 4) << 4);
            bf16x8 a[4], b[4];
            #pragma unroll
            for (int x = 0; x < 4; x++) {
                a[x] = *(const bf16x8*)((char*)As + swz128(wm + (x << 4) + (l & 15), kb));
                b[x] = *(const bf16x8*)((char*)Ws + swz128(wn + (x << 4) + (l & 15), kb));
            }
            #pragma unroll
            for (int i = 0; i < 4; i++)
            #pragma unroll
            for (int j = 0; j < 4; j++)
                acc[i][j] = __builtin_amdgcn_mfma_f32_16x16x32_bf16(a[i], b[j], acc[i][j], 0, 0, 0);
        }
    }
    #pragma unroll
    for (int mf = 0; mf < 4; mf++)
    #pragma unroll
    for (int nf = 0; nf < 4; nf++) {
        int col  = n0 + wn + (nf << 4) + (l & 15);
        int row0 = i0 + wm + (mf << 4) + ((l >> 4) << 2);
        int n = col >> 5, d = col & 31;
        #pragma unroll
        for (int r = 0; r < 4; r++) {
            int i = row0 + r;
            pvout[((size_t)n * LDIM + i) * CDIM + (h << 5) + d] = f2bf(acc[mf][nf][r]);
        }
    }
}

extern "C" void kernel_launch(void* const* d_in, const int* in_sizes, int n_in,
                              void* d_out, int out_size, void* d_ws, size_t ws_size,
                              hipStream_t stream)
{
    const float* pair     = (const float*)d_in[0];
    const float* rbf_feat = (const float*)d_in[1];
    const float* emb_b    = (const float*)d_in[3];
    const float* proj_b   = (const float*)d_in[5];
    const float* ff_ln_w  = (const float*)d_in[30];
    const float* ff_ln_b  = (const float*)d_in[31];
    const float* ff_b1    = (const float*)d_in[33];
    const float* ff_b2    = (const float*)d_in[35];
    float* out = (float*)d_out;

    ushort* R0 = (ushort*)d_ws;
    ushort* R1 = R0 + (size_t)LL*CDIM;
    ushort* R2 = R1 + (size_t)LL*CDIM;
    ushort* R3 = R2 + (size_t)LL*CDIM;
    float*  partialb = (float*)(R3 + (size_t)LL*CDIM);
    float*  battn_r  = partialb + (size_t)NCHUNK*HN*LL;
    float*  battn_c  = battn_r  + (size_t)HN*LL;
    ushort* attn_bf  = (ushort*)(battn_c + (size_t)HN*LL);
    ushort* wt       = attn_bf + (size_t)HN*LL;

    size_t need_bytes = (size_t)4*LL*CDIM*2 + ((size_t)NCHUNK*HN*LL + 2*(size_t)HN*LL)*4
                      + (size_t)HN*LL*2 + (size_t)262144*2;
    if (ws_size < need_bytes) return;

    const size_t WS = 16384;
    ushort* wt_emb  = wt;
    ushort* wt_proj = wt + WS;
    ushort* wt_ff1  = wt + 12*WS;
    ushort* wt_ff2  = wt + 12*WS + 32768;

    const float SCALE = 0.17677669529663687f;  // 32^-0.5

    wprep_kernel<<<dim3(128, 14), 256, 0, stream>>>(wt,
        (const float*)d_in[2], (const float*)d_in[4],
        (const float*)d_in[10], (const float*)d_in[11], (const float*)d_in[12],
        (const float*)d_in[14], (const float*)d_in[16],
        (const float*)d_in[22], (const float*)d_in[23], (const float*)d_in[24],
        (const float*)d_in[26], (const float*)d_in[28],
        (const float*)d_in[32], (const float*)d_in[34]);

    // rbf = relu(rbf_feat@emb+eb)@proj+pb : hidden bf16 -> R3; rbf fp32 spans R0+R1
    mgemm64<1,0,1,0><<<dim3(1,1152), 256, 0, stream>>>(rbf_feat, wt_emb, emb_b, nullptr, nullptr, R3,
        nullptr, nullptr, nullptr, 128, 128, 36, 1.f, 0, 0);
    mgemm64<0,1,0,0><<<dim3(1,1152), 256, 0, stream>>>(R3, wt_proj, proj_b, nullptr, nullptr, (float*)R0,
        nullptr, nullptr, nullptr, 128, 128, 128, 1.f, 0, 0);
    // both frames' pairwise bias in ONE pass over rbf
    battn2_kernel<<<LL/4, 256, 0, stream>>>((const float*)R0, battn_r, battn_c,
        (const float*)d_in[8],  (const float*)d_in[9],  (const float*)d_in[13],
        (const float*)d_in[20], (const float*)d_in[21], (const float*)d_in[25]);

    // initial row-pass xln (transposed frame) -> R3
    lnpack_kernel<<<LL/4, 256, 0, stream>>>(pair, R3, (const float*)d_in[6], (const float*)d_in[7], 1);

    ushort* XLN = R3;
    for (int pass = 0; pass < 2; pass++) {
        const float* const* wp = (const float* const*)(d_in + (pass ? 18 : 6));
        int trans = pass ? 0 : 1;
        const float* P = pass ? (const float*)out : pair;
        const float* battnb = pass ? battn_c : battn_r;
        int ws0 = pass ? 7 : 2;   // wq slot; wk,wv,wg,wo follow
        const float* nlw = pass ? ff_ln_w : (const float*)d_in[18];
        const float* nlb = pass ? ff_ln_b : (const float*)d_in[19];
        ushort* Qb   = R0;
        ushort* Kb2  = pass ? R3 : R1;
        ushort* VTb  = R2;
        ushort* PVb  = R0;
        ushort* XLNn = pass ? R3 : R1;
        // q,k,v,g off one staged A (g overwrites XLN in place — blocks only touch own rows)
        qkv4_gemm<<<1152, 256, 0, stream>>>(XLN, wt + ws0*WS, Qb, Kb2, VTb, XLN, wp[9], SCALE, 1.f/LDIM);
        score128<<<dim3(9, HN, NCHUNK), 256, 0, stream>>>(Qb, Kb2, partialb);
        softmax_kernel<<<HN*LDIM, 64, 0, stream>>>(partialb, battnb, attn_bf);
        pvg_gemm<<<dim3(96, 3, 4), 256, 0, stream>>>(attn_bf, VTb, PVb);
        // pair_out = residual + (g .* pv)@wo + bo ; fused LN -> next xln
        mgemm64<0,2,3,1><<<dim3(1,1152), 256, 0, stream>>>(PVb, wt + (ws0+4)*WS, wp[11], XLN, P, out,
            nlw, nlb, XLNn, 128, 128, 128, 1.f, trans, trans);
        XLN = XLNn;
    }

    // FFN: out += relu(xln@w1+b1)@w2+b2  (h1 bf16 [LL][256] spans R0+R1)
    mgemm64<1,1,1,0><<<dim3(2,1152), 256, 0, stream>>>(XLN, wt_ff1, ff_b1, nullptr, nullptr, R0,
        nullptr, nullptr, nullptr, 256, 128, 128, 1.f, 0, 0);
    mgemm64<0,1,0,0><<<dim3(1,1152), 256, 0, stream>>>(R0, wt_ff2, ff_b2, nullptr, out, out,
        nullptr, nullptr, nullptr, 128, 256, 256, 1.f, 0, 0);
}

// Round 13
// 816.890 us; speedup vs baseline: 1.1382x; 1.0561x over previous
//
#include <hip/hip_runtime.h>
#include <hip/hip_bf16.h>
#include <math.h>

#define LDIM 384
#define CDIM 128
#define HN 4
#define LL (LDIM*LDIM)
#define NCHUNK 8
#define VTPLANE ((size_t)12288*384)

typedef __attribute__((ext_vector_type(8))) short bf16x8;
typedef __attribute__((ext_vector_type(4))) float f32x4;

__device__ __forceinline__ ushort f2bf(float x) {
    union { __hip_bfloat16 h; ushort u; } cv;
    cv.h = __float2bfloat16(x);
    return cv.u;
}
__device__ __forceinline__ float bf2f(ushort u) {
    union { unsigned int i; float f; } cv; cv.i = ((unsigned int)u) << 16; return cv.f;
}
__device__ __forceinline__ int swz256(int row, int cb) { return (row * 256 + cb) ^ ((row & 7) << 4); }
__device__ __forceinline__ int swz128(int row, int cb) { return (row * 128 + cb) ^ ((row & 7) << 4); }
__device__ __forceinline__ size_t trow(int row) { return (size_t)(row % LDIM) * LDIM + row / LDIM; }

// ---------------- weight prep: fp32 [K][N] -> bf16 [N][KP] (zero-padded K) ----------------
__global__ __launch_bounds__(256) void wprep_kernel(ushort* __restrict__ wt,
    const float* emb_w, const float* proj_w,
    const float* rwq, const float* rwk, const float* rwv, const float* rwg, const float* rwo,
    const float* cwq, const float* cwk, const float* cwv, const float* cwg, const float* cwo,
    const float* ffw1, const float* ffw2)
{
    int y = blockIdx.y;
    const float* src; int N, K, KP; size_t off;
    switch (y) {
        case 0:  src = emb_w;  N = 128; K = 36;  KP = 128; off = 0;         break;
        case 1:  src = proj_w; N = 128; K = 128; KP = 128; off = 16384;     break;
        case 2:  src = rwq;    N = 128; K = 128; KP = 128; off = 2*16384;   break;
        case 3:  src = rwk;    N = 128; K = 128; KP = 128; off = 3*16384;   break;
        case 4:  src = rwv;    N = 128; K = 128; KP = 128; off = 4*16384;   break;
        case 5:  src = rwg;    N = 128; K = 128; KP = 128; off = 5*16384;   break;
        case 6:  src = rwo;    N = 128; K = 128; KP = 128; off = 6*16384;   break;
        case 7:  src = cwq;    N = 128; K = 128; KP = 128; off = 7*16384;   break;
        case 8:  src = cwk;    N = 128; K = 128; KP = 128; off = 8*16384;   break;
        case 9:  src = cwv;    N = 128; K = 128; KP = 128; off = 9*16384;   break;
        case 10: src = cwg;    N = 128; K = 128; KP = 128; off = 10*16384;  break;
        case 11: src = cwo;    N = 128; K = 128; KP = 128; off = 11*16384;  break;
        case 12: src = ffw1;   N = 256; K = 128; KP = 128; off = 12*16384;  break;
        default: src = ffw2;   N = 128; K = 256; KP = 256; off = 12*16384 + 32768; break;
    }
    int e = blockIdx.x * 256 + threadIdx.x;
    if (e >= N * KP) return;
    int nn = e / KP, kp = e - nn * KP;
    float v = (kp < K) ? src[(size_t)kp * N + nn] : 0.f;
    wt[off + e] = f2bf(v);
}

// ------- LN + bf16 pack: coalesced read of src row p, write to dst row trans(p) -------
__global__ __launch_bounds__(256) void lnpack_kernel(const float* __restrict__ src,
    ushort* __restrict__ dst, const float* __restrict__ w, const float* __restrict__ b, int trans)
{
    int p = (blockIdx.x << 2) + (threadIdx.x >> 6);
    int lane = threadIdx.x & 63;
    float2 v = *(const float2*)(src + (size_t)p * CDIM + (lane << 1));
    float s  = v.x + v.y;
    float ss = v.x*v.x + v.y*v.y;
    #pragma unroll
    for (int off = 32; off; off >>= 1) { s += __shfl_xor(s, off, 64); ss += __shfl_xor(ss, off, 64); }
    float mean = s * (1.0f/CDIM);
    float var  = ss * (1.0f/CDIM) - mean*mean;
    float rstd = rsqrtf(var + 1e-5f);
    int q = trans ? ((p % LDIM) * LDIM + p / LDIM) : p;
    ushort2 o;
    o.x = f2bf((v.x - mean) * rstd * w[lane<<1]     + b[lane<<1]);
    o.y = f2bf((v.y - mean) * rstd * w[(lane<<1)+1] + b[(lane<<1)+1]);
    *(ushort2*)(dst + (size_t)q * CDIM + (lane << 1)) = o;
}

// ------- dual bias-attention: read rbf row p=(a,b) ONCE, shared LN stats, write BOTH frames -------
__global__ __launch_bounds__(256) void battn2_kernel(const float* __restrict__ rbf,
    float* __restrict__ battn_r, float* __restrict__ battn_c,
    const float* __restrict__ rlnw, const float* __restrict__ rlnb, const float* __restrict__ rwb,
    const float* __restrict__ clnw, const float* __restrict__ clnb, const float* __restrict__ cwb)
{
    int p = (blockIdx.x << 2) + (threadIdx.x >> 6);
    int lane = threadIdx.x & 63;
    int a = p / LDIM, b2 = p % LDIM;
    float2 v = *(const float2*)(rbf + (size_t)p * CDIM + (lane << 1));
    float s = v.x + v.y, ss = v.x*v.x + v.y*v.y;
    #pragma unroll
    for (int off = 32; off; off >>= 1) { s += __shfl_xor(s, off, 64); ss += __shfl_xor(ss, off, 64); }
    float mean = s*(1.f/CDIM), var = ss*(1.f/CDIM) - mean*mean, rstd = rsqrtf(var + 1e-5f);
    float c0x = (v.x - mean) * rstd, c1x = (v.y - mean) * rstd;
    int e0 = lane << 1, e1 = e0 + 1;
    float xr0 = c0x * rlnw[e0] + rlnb[e0], xr1 = c1x * rlnw[e1] + rlnb[e1];
    float xc0 = c0x * clnw[e0] + clnb[e0], xc1 = c1x * clnw[e1] + clnb[e1];
    int q0 = e0 * HN, q1 = e1 * HN;
    float r0 = xr0*rwb[q0+0] + xr1*rwb[q1+0];
    float r1 = xr0*rwb[q0+1] + xr1*rwb[q1+1];
    float r2 = xr0*rwb[q0+2] + xr1*rwb[q1+2];
    float r3 = xr0*rwb[q0+3] + xr1*rwb[q1+3];
    float c0 = xc0*cwb[q0+0] + xc1*cwb[q1+0];
    float c1 = xc0*cwb[q0+1] + xc1*cwb[q1+1];
    float c2 = xc0*cwb[q0+2] + xc1*cwb[q1+2];
    float c3 = xc0*cwb[q0+3] + xc1*cwb[q1+3];
    #pragma unroll
    for (int off = 32; off; off >>= 1) {
        r0 += __shfl_xor(r0, off, 64); r1 += __shfl_xor(r1, off, 64);
        r2 += __shfl_xor(r2, off, 64); r3 += __shfl_xor(r3, off, 64);
        c0 += __shfl_xor(c0, off, 64); c1 += __shfl_xor(c1, off, 64);
        c2 += __shfl_xor(c2, off, 64); c3 += __shfl_xor(c3, off, 64);
    }
    if (lane == 0) {
        battn_r[((size_t)0*LDIM + b2)*LDIM + a] = r0;
        battn_r[((size_t)1*LDIM + b2)*LDIM + a] = r1;
        battn_r[((size_t)2*LDIM + b2)*LDIM + a] = r2;
        battn_r[((size_t)3*LDIM + b2)*LDIM + a] = r3;
        battn_c[((size_t)0*LDIM + a)*LDIM + b2] = c0;
        battn_c[((size_t)1*LDIM + a)*LDIM + b2] = c1;
        battn_c[((size_t)2*LDIM + a)*LDIM + b2] = c2;
        battn_c[((size_t)3*LDIM + a)*LDIM + b2] = c3;
    }
}

// ------- BK=64 128x128-tile MFMA GEMM (round-7 verified config). -------
// AMODE: 0 fp32, 1 bf16, 2 bf16 gated. OUTMODE: 0 fp32 (+res), 1 bf16, 3 fp32 w/ rtrans/otrans.
// LNOUT: fuse LN over 128 out channels (N=128, grid.x=1, OUTMODE3): writes out fp32 + xln bf16.
template<int ACT, int AMODE, int OUTMODE, int LNOUT>
__global__ __launch_bounds__(256) void mgemm64(
    const void* __restrict__ Ain, const ushort* __restrict__ Wt,
    const float* __restrict__ bias, const ushort* __restrict__ gmul,
    const float* __restrict__ res, void* __restrict__ Cout,
    const float* __restrict__ lnw2, const float* __restrict__ lnb2, ushort* __restrict__ xln,
    int N, int KP, int lda, float alpha, int rtrans, int otrans)
{
    __shared__ ushort As[128*64];
    __shared__ ushort Ws[128*64];
    int t = threadIdx.x, l = t & 63, wv = t >> 6;
    int m0 = blockIdx.y << 7, n0 = blockIdx.x << 7;
    int wm = (wv >> 1) << 6, wn = (wv & 1) << 6;
    int sr = t >> 1;            // staging row
    int sh = (t & 1) << 5;      // k offset (shorts)
    f32x4 acc[4][4] = {};
    for (int k0 = 0; k0 < KP; k0 += 64) {
        if (k0) __syncthreads();
        if (AMODE == 1) {
            const ushort* ap = (const ushort*)Ain + (size_t)(m0 + sr) * lda + k0 + sh;
            #pragma unroll
            for (int u = 0; u < 4; u++)
                *(int4*)((char*)As + swz128(sr, (sh << 1) + (u << 4))) = *(const int4*)(ap + (u << 3));
        } else if (AMODE == 2) {
            const ushort* ap = (const ushort*)Ain + (size_t)(m0 + sr) * lda + k0 + sh;
            const ushort* gp = gmul + (size_t)(m0 + sr) * lda + k0 + sh;
            #pragma unroll
            for (int u = 0; u < 4; u++) {
                int4 av = *(const int4*)(ap + (u << 3));
                int4 gv = *(const int4*)(gp + (u << 3));
                ushort* au = (ushort*)&av; ushort* gu = (ushort*)&gv;
                short v8[8];
                #pragma unroll
                for (int e = 0; e < 8; e++) v8[e] = (short)f2bf(bf2f(au[e]) * bf2f(gu[e]));
                *(int4*)((char*)As + swz128(sr, (sh << 1) + (u << 4))) = *(int4*)v8;
            }
        } else {
            const float* ap = (const float*)Ain + (size_t)(m0 + sr) * lda;
            #pragma unroll
            for (int u = 0; u < 4; u++) {
                short v8[8];
                #pragma unroll
                for (int e = 0; e < 8; e++) {
                    int c = k0 + sh + (u << 3) + e;
                    v8[e] = (short)f2bf((c < lda) ? ap[c] : 0.f);
                }
                *(int4*)((char*)As + swz128(sr, (sh << 1) + (u << 4))) = *(int4*)v8;
            }
        }
        {
            const ushort* wp2 = Wt + (size_t)(n0 + sr) * KP + k0 + sh;
            #pragma unroll
            for (int u = 0; u < 4; u++)
                *(int4*)((char*)Ws + swz128(sr, (sh << 1) + (u << 4))) = *(const int4*)(wp2 + (u << 3));
        }
        __syncthreads();
        #pragma unroll
        for (int ks = 0; ks < 2; ks++) {
            int kb = (ks << 6) + ((l >> 4) << 4);
            bf16x8 a[4], b[4];
            #pragma unroll
            for (int x = 0; x < 4; x++) {
                a[x] = *(const bf16x8*)((char*)As + swz128(wm + (x << 4) + (l & 15), kb));
                b[x] = *(const bf16x8*)((char*)Ws + swz128(wn + (x << 4) + (l & 15), kb));
            }
            #pragma unroll
            for (int i = 0; i < 4; i++)
            #pragma unroll
            for (int j = 0; j < 4; j++)
                acc[i][j] = __builtin_amdgcn_mfma_f32_16x16x32_bf16(a[i], b[j], acc[i][j], 0, 0, 0);
        }
    }
    if (LNOUT) {
        #pragma unroll
        for (int mf = 0; mf < 4; mf++)
        #pragma unroll
        for (int nf = 0; nf < 4; nf++) {
            int col  = wn + (nf << 4) + (l & 15);
            int row0 = m0 + wm + (mf << 4) + ((l >> 4) << 2);
            float bb = bias ? bias[col] : 0.f;
            #pragma unroll
            for (int r = 0; r < 4; r++) {
                int row = row0 + r;
                size_t rrow = rtrans ? trow(row) : (size_t)row;
                acc[mf][nf][r] = acc[mf][nf][r] * alpha + bb + (res ? res[rrow * CDIM + col] : 0.f);
            }
        }
        float ps[4][4], pq[4][4];
        #pragma unroll
        for (int mf = 0; mf < 4; mf++)
        #pragma unroll
        for (int r = 0; r < 4; r++) {
            float s = 0.f, q = 0.f;
            #pragma unroll
            for (int nf = 0; nf < 4; nf++) { float v = acc[mf][nf][r]; s += v; q += v * v; }
            ps[mf][r] = s; pq[mf][r] = q;
        }
        #pragma unroll
        for (int off = 1; off < 16; off <<= 1)
        #pragma unroll
        for (int mf = 0; mf < 4; mf++)
        #pragma unroll
        for (int r = 0; r < 4; r++) {
            ps[mf][r] += __shfl_xor(ps[mf][r], off, 64);
            pq[mf][r] += __shfl_xor(pq[mf][r], off, 64);
        }
        __syncthreads();
        float* lnbuf = (float*)As;       // [2][128][2]
        if ((l & 15) == 0) {
            #pragma unroll
            for (int mf = 0; mf < 4; mf++)
            #pragma unroll
            for (int r = 0; r < 4; r++) {
                int rl = wm + (mf << 4) + ((l >> 4) << 2) + r;
                lnbuf[(((wv & 1) << 7) + rl) * 2 + 0] = ps[mf][r];
                lnbuf[(((wv & 1) << 7) + rl) * 2 + 1] = pq[mf][r];
            }
        }
        __syncthreads();
        #pragma unroll
        for (int mf = 0; mf < 4; mf++)
        #pragma unroll
        for (int nf = 0; nf < 4; nf++) {
            int col  = wn + (nf << 4) + (l & 15);
            int row0 = m0 + wm + (mf << 4) + ((l >> 4) << 2);
            float lw = lnw2[col], lb = lnb2[col];
            #pragma unroll
            for (int r = 0; r < 4; r++) {
                int row = row0 + r;
                int rl  = wm + (mf << 4) + ((l >> 4) << 2) + r;
                float s  = lnbuf[rl * 2 + 0] + lnbuf[(256 + rl * 2) + 0];
                float q  = lnbuf[rl * 2 + 1] + lnbuf[(256 + rl * 2) + 1];
                float mean = s * (1.f/CDIM);
                float var  = q * (1.f/CDIM) - mean * mean;
                float rstd = rsqrtf(var + 1e-5f);
                float o = acc[mf][nf][r];
                size_t orow = otrans ? trow(row) : (size_t)row;
                ((float*)Cout)[orow * CDIM + col] = o;
                xln[orow * CDIM + col] = f2bf((o - mean) * rstd * lw + lb);
            }
        }
    } else {
        #pragma unroll
        for (int mf = 0; mf < 4; mf++)
        #pragma unroll
        for (int nf = 0; nf < 4; nf++) {
            int col  = n0 + wn + (nf << 4) + (l & 15);
            int row0 = m0 + wm + (mf << 4) + ((l >> 4) << 2);
            float bb = bias ? bias[col] : 0.f;
            #pragma unroll
            for (int r = 0; r < 4; r++) {
                int row = row0 + r;
                float v = acc[mf][nf][r] * alpha + bb;
                if (ACT == 1) v = fmaxf(v, 0.f);
                if (ACT == 2) v = 1.f / (1.f + __expf(-v));
                if (OUTMODE == 0) {
                    float o = v + (res ? res[(size_t)row * N + col] : 0.f);
                    ((float*)Cout)[(size_t)row * N + col] = o;
                } else if (OUTMODE == 1) {
                    ((ushort*)Cout)[(size_t)row * N + col] = f2bf(v);
                } else {
                    size_t orow = otrans ? trow(row) : (size_t)row;
                    size_t rrow = rtrans ? trow(row) : (size_t)row;
                    float o = v + (res ? res[rrow * N + col] : 0.f);
                    ((float*)Cout)[orow * N + col] = o;
                }
            }
        }
    }
}

// ------- q,k,v,g: M=64 tile (As 16KB + Ws 32KB = 48KB -> 3 blocks/CU), 2304 blocks -------
__global__ __launch_bounds__(256) void qkv4_gemm(
    const ushort* __restrict__ A, const ushort* __restrict__ wt4,
    ushort* __restrict__ qo, ushort* __restrict__ ko, ushort* __restrict__ vt,
    ushort* __restrict__ go, const float* __restrict__ bg,
    float scale_q, float scale_k)
{
    __shared__ ushort As[64*128];    // 16 KB
    __shared__ ushort Ws[128*128];   // 32 KB
    int t = threadIdx.x, l = t & 63, wv = t >> 6;
    int m0 = blockIdx.x << 6;
    int wm = (wv >> 1) << 5;         // 0 / 32
    int wn = (wv & 1) << 6;          // 0 / 64
    {
        int sr = t >> 2, scb = (t & 3) << 6;
        const ushort* ap = A + (size_t)(m0 + sr) * CDIM + (scb >> 1);
        #pragma unroll
        for (int u = 0; u < 4; u++)
            *(int4*)((char*)As + swz256(sr, scb + (u << 4))) = *(const int4*)(ap + (u << 3));
    }
    for (int comp = 0; comp < 4; comp++) {
        if (comp) __syncthreads();
        {
            int sr = t >> 1, scb = (t & 1) << 7;
            const ushort* wp2 = wt4 + (size_t)comp * 16384 + (size_t)sr * CDIM + (scb >> 1);
            #pragma unroll
            for (int u = 0; u < 8; u++)
                *(int4*)((char*)Ws + swz256(sr, scb + (u << 4))) = *(const int4*)(wp2 + (u << 3));
        }
        __syncthreads();
        f32x4 acc[2][4] = {};
        #pragma unroll
        for (int ks = 0; ks < 4; ks++) {
            int kb = (ks << 6) + ((l >> 4) << 4);
            bf16x8 a[2], b[4];
            #pragma unroll
            for (int x = 0; x < 2; x++)
                a[x] = *(const bf16x8*)((char*)As + swz256(wm + (x << 4) + (l & 15), kb));
            #pragma unroll
            for (int x = 0; x < 4; x++)
                b[x] = *(const bf16x8*)((char*)Ws + swz256(wn + (x << 4) + (l & 15), kb));
            #pragma unroll
            for (int i = 0; i < 2; i++)
            #pragma unroll
            for (int j = 0; j < 4; j++)
                acc[i][j] = __builtin_amdgcn_mfma_f32_16x16x32_bf16(a[i], b[j], acc[i][j], 0, 0, 0);
        }
        #pragma unroll
        for (int mf = 0; mf < 2; mf++)
        #pragma unroll
        for (int nf = 0; nf < 4; nf++) {
            int col  = wn + (nf << 4) + (l & 15);
            int row0 = m0 + wm + (mf << 4) + ((l >> 4) << 2);
            if (comp == 0) {
                #pragma unroll
                for (int r = 0; r < 4; r++)
                    qo[(size_t)(row0 + r) * CDIM + col] = f2bf(acc[mf][nf][r] * scale_q);
            } else if (comp == 1) {
                #pragma unroll
                for (int r = 0; r < 4; r++)
                    ko[(size_t)(row0 + r) * CDIM + col] = f2bf(acc[mf][nf][r] * scale_k);
            } else if (comp == 2) {
                ushort4 pk;
                #pragma unroll
                for (int r = 0; r < 4; r++) ((ushort*)&pk)[r] = f2bf(acc[mf][nf][r]);
                int n = row0 / LDIM, j = row0 % LDIM;   // 64-row tiles never cross n
                *(ushort4*)&vt[((size_t)(col >> 5) * 12288 + (size_t)n * 32 + (col & 31)) * 384 + j] = pk;
            } else {
                float bb = bg[col];
                #pragma unroll
                for (int r = 0; r < 4; r++) {
                    float v = acc[mf][nf][r] + bb;
                    go[(size_t)(row0 + r) * CDIM + col] = f2bf(1.f / (1.f + __expf(-v)));
                }
            }
        }
    }
}

// ------- tied scores (verified round-7 3D grid): partial[cz,h,i,j] -------
__global__ __launch_bounds__(256) void score128(const ushort* __restrict__ Q,
    const ushort* __restrict__ Kb, float* __restrict__ partial)
{
    __shared__ ushort As[128*128];
    __shared__ ushort Bs[128*128];
    int t = threadIdx.x, l = t & 63, wv = t >> 6;
    int ti = blockIdx.x / 3, tj = blockIdx.x % 3;
    int h = blockIdx.y, cz = blockIdx.z;
    int i0 = ti << 7, j0 = tj << 7;
    int wm = (wv >> 1) << 6, wn = (wv & 1) << 6;
    int sr = t >> 1, half = t & 1;
    f32x4 acc[4][4] = {};
    for (int it = 0; it < 12; it++) {
        if (it) __syncthreads();
        int nb = cz * 48 + (it << 2);
        #pragma unroll
        for (int e = 0; e < 2; e++) {
            int nq = (half << 1) + e;
            const ushort* qp = Q  + ((size_t)(nb + nq) * LDIM + i0 + sr) * CDIM + (h << 5);
            const ushort* kp = Kb + ((size_t)(nb + nq) * LDIM + j0 + sr) * CDIM + (h << 5);
            *(int4*)((char*)As + swz256(sr, (nq << 6) +  0)) = *(const int4*)qp;
            *(int4*)((char*)As + swz256(sr, (nq << 6) + 16)) = *(const int4*)(qp + 8);
            *(int4*)((char*)As + swz256(sr, (nq << 6) + 32)) = *(const int4*)(qp + 16);
            *(int4*)((char*)As + swz256(sr, (nq << 6) + 48)) = *(const int4*)(qp + 24);
            *(int4*)((char*)Bs + swz256(sr, (nq << 6) +  0)) = *(const int4*)kp;
            *(int4*)((char*)Bs + swz256(sr, (nq << 6) + 16)) = *(const int4*)(kp + 8);
            *(int4*)((char*)Bs + swz256(sr, (nq << 6) + 32)) = *(const int4*)(kp + 16);
            *(int4*)((char*)Bs + swz256(sr, (nq << 6) + 48)) = *(const int4*)(kp + 24);
        }
        __syncthreads();
        #pragma unroll
        for (int ks = 0; ks < 4; ks++) {
            int kb = (ks << 6) + ((l >> 4) << 4);
            bf16x8 a[4], b[4];
            #pragma unroll
            for (int x = 0; x < 4; x++) {
                a[x] = *(const bf16x8*)((char*)As + swz256(wm + (x << 4) + (l & 15), kb));
                b[x] = *(const bf16x8*)((char*)Bs + swz256(wn + (x << 4) + (l & 15), kb));
            }
            #pragma unroll
            for (int i = 0; i < 4; i++)
            #pragma unroll
            for (int j = 0; j < 4; j++)
                acc[i][j] = __builtin_amdgcn_mfma_f32_16x16x32_bf16(a[i], b[j], acc[i][j], 0, 0, 0);
        }
    }
    #pragma unroll
    for (int mf = 0; mf < 4; mf++)
    #pragma unroll
    for (int nf = 0; nf < 4; nf++) {
        int j = j0 + wn + (nf << 4) + (l & 15);
        int i = i0 + wm + (mf << 4) + ((l >> 4) << 2);
        #pragma unroll
        for (int r = 0; r < 4; r++)
            partial[((size_t)(cz*HN + h)*LDIM + i + r)*LDIM + j] = acc[mf][nf][r];
    }
}

// ---------------- softmax over j (chunk reduce + bias) -> bf16 ----------------
__global__ __launch_bounds__(64) void softmax_kernel(
    const float* __restrict__ partial, const float* __restrict__ battn, ushort* __restrict__ attn)
{
    int hi = blockIdx.x;
    int l = threadIdx.x;
    float s[6];
    #pragma unroll
    for (int u = 0; u < 6; u++) {
        size_t idx = (size_t)hi * LDIM + l + (u << 6);
        float v = battn[idx];
        #pragma unroll
        for (int c = 0; c < NCHUNK; c++) v += partial[(size_t)c * HN * LL + idx];
        s[u] = v;
    }
    float m = s[0];
    #pragma unroll
    for (int u = 1; u < 6; u++) m = fmaxf(m, s[u]);
    #pragma unroll
    for (int off = 32; off; off >>= 1) m = fmaxf(m, __shfl_xor(m, off, 64));
    float sum = 0.f;
    #pragma unroll
    for (int u = 0; u < 6; u++) { s[u] = __expf(s[u] - m); sum += s[u]; }
    #pragma unroll
    for (int off = 32; off; off >>= 1) sum += __shfl_xor(sum, off, 64);
    float inv = 1.f / sum;
    #pragma unroll
    for (int u = 0; u < 6; u++) attn[(size_t)hi * LDIM + l + (u << 6)] = f2bf(s[u] * inv);
}

// ------- PV per-head GEMM (BK=64): pvout[(n,i),h*32+d] -------
__global__ __launch_bounds__(256) void pvg_gemm(const ushort* __restrict__ attn,
    const ushort* __restrict__ vt, ushort* __restrict__ pvout)
{
    __shared__ ushort As[128*64];
    __shared__ ushort Ws[128*64];
    int t = threadIdx.x, l = t & 63, wv = t >> 6;
    int n0 = blockIdx.x << 7;
    int i0 = blockIdx.y << 7;
    int h  = blockIdx.z;
    const ushort* abase = attn + (size_t)h * LL;
    const ushort* bbase = vt + (size_t)h * VTPLANE;
    int wm = (wv >> 1) << 6, wn = (wv & 1) << 6;
    int sr = t >> 1, sh = (t & 1) << 5;
    f32x4 acc[4][4] = {};
    for (int k0 = 0; k0 < LDIM; k0 += 64) {
        if (k0) __syncthreads();
        {
            const ushort* ap = abase + (size_t)(i0 + sr) * LDIM + k0 + sh;
            const ushort* bp = bbase + (size_t)(n0 + sr) * LDIM + k0 + sh;
            #pragma unroll
            for (int u = 0; u < 4; u++) {
                *(int4*)((char*)As + swz128(sr, (sh << 1) + (u << 4))) = *(const int4*)(ap + (u << 3));
                *(int4*)((char*)Ws + swz128(sr, (sh << 1) + (u << 4))) = *(const int4*)(bp + (u << 3));
            }
        }
        __syncthreads();
        #pragma unroll
        for (int ks = 0; ks < 2; ks++) {
            int kb = (ks << 6) + ((l >> 4) << 4);
            bf16x8 a[4], b[4];
            #pragma unroll
            for (int x = 0; x < 4; x++) {
                a[x] = *(const bf16x8*)((char*)As + swz128(wm + (x << 4) + (l & 15), kb));
                b[x] = *(const bf16x8*)((char*)Ws + swz128(wn + (x << 4) + (l & 15), kb));
            }
            #pragma unroll
            for (int i = 0; i < 4; i++)
            #pragma unroll
            for (int j = 0; j < 4; j++)
                acc[i][j] = __builtin_amdgcn_mfma_f32_16x16x32_bf16(a[i], b[j], acc[i][j], 0, 0, 0);
        }
    }
    #pragma unroll
    for (int mf = 0; mf < 4; mf++)
    #pragma unroll
    for (int nf = 0; nf < 4; nf++) {
        int col  = n0 + wn + (nf << 4) + (l & 15);
        int row0 = i0 + wm + (mf << 4) + ((l >> 4) << 2);
        int n = col >> 5, d = col & 31;
        #pragma unroll
        for (int r = 0; r < 4; r++) {
            int i = row0 + r;
            pvout[((size_t)n * LDIM + i) * CDIM + (h << 5) + d] = f2bf(acc[mf][nf][r]);
        }
    }
}

extern "C" void kernel_launch(void* const* d_in, const int* in_sizes, int n_in,
                              void* d_out, int out_size, void* d_ws, size_t ws_size,
                              hipStream_t stream)
{
    const float* pair     = (const float*)d_in[0];
    const float* rbf_feat = (const float*)d_in[1];
    const float* emb_b    = (const float*)d_in[3];
    const float* proj_b   = (const float*)d_in[5];
    const float* ff_ln_w  = (const float*)d_in[30];
    const float* ff_ln_b  = (const float*)d_in[31];
    const float* ff_b1    = (const float*)d_in[33];
    const float* ff_b2    = (const float*)d_in[35];
    float* out = (float*)d_out;

    ushort* R0 = (ushort*)d_ws;
    ushort* R1 = R0 + (size_t)LL*CDIM;
    ushort* R2 = R1 + (size_t)LL*CDIM;
    ushort* R3 = R2 + (size_t)LL*CDIM;
    float*  partialb = (float*)(R3 + (size_t)LL*CDIM);
    float*  battn_r  = partialb + (size_t)NCHUNK*HN*LL;
    float*  battn_c  = battn_r  + (size_t)HN*LL;
    ushort* attn_bf  = (ushort*)(battn_c + (size_t)HN*LL);
    ushort* wt       = attn_bf + (size_t)HN*LL;

    size_t need_bytes = (size_t)4*LL*CDIM*2 + ((size_t)NCHUNK*HN*LL + 2*(size_t)HN*LL)*4
                      + (size_t)HN*LL*2 + (size_t)262144*2;
    if (ws_size < need_bytes) return;

    const size_t WS = 16384;
    ushort* wt_emb  = wt;
    ushort* wt_proj = wt + WS;
    ushort* wt_ff1  = wt + 12*WS;
    ushort* wt_ff2  = wt + 12*WS + 32768;

    const float SCALE = 0.17677669529663687f;  // 32^-0.5

    wprep_kernel<<<dim3(128, 14), 256, 0, stream>>>(wt,
        (const float*)d_in[2], (const float*)d_in[4],
        (const float*)d_in[10], (const float*)d_in[11], (const float*)d_in[12],
        (const float*)d_in[14], (const float*)d_in[16],
        (const float*)d_in[22], (const float*)d_in[23], (const float*)d_in[24],
        (const float*)d_in[26], (const float*)d_in[28],
        (const float*)d_in[32], (const float*)d_in[34]);

    // rbf = relu(rbf_feat@emb+eb)@proj+pb : hidden bf16 -> R3; rbf fp32 spans R0+R1
    mgemm64<1,0,1,0><<<dim3(1,1152), 256, 0, stream>>>(rbf_feat, wt_emb, emb_b, nullptr, nullptr, R3,
        nullptr, nullptr, nullptr, 128, 128, 36, 1.f, 0, 0);
    mgemm64<0,1,0,0><<<dim3(1,1152), 256, 0, stream>>>(R3, wt_proj, proj_b, nullptr, nullptr, (float*)R0,
        nullptr, nullptr, nullptr, 128, 128, 128, 1.f, 0, 0);
    // both frames' pairwise bias in ONE pass over rbf
    battn2_kernel<<<LL/4, 256, 0, stream>>>((const float*)R0, battn_r, battn_c,
        (const float*)d_in[8],  (const float*)d_in[9],  (const float*)d_in[13],
        (const float*)d_in[20], (const float*)d_in[21], (const float*)d_in[25]);

    // initial row-pass xln (transposed frame) -> R3
    lnpack_kernel<<<LL/4, 256, 0, stream>>>(pair, R3, (const float*)d_in[6], (const float*)d_in[7], 1);

    ushort* XLN = R3;
    for (int pass = 0; pass < 2; pass++) {
        const float* const* wp = (const float* const*)(d_in + (pass ? 18 : 6));
        int trans = pass ? 0 : 1;
        const float* P = pass ? (const float*)out : pair;
        const float* battnb = pass ? battn_c : battn_r;
        int ws0 = pass ? 7 : 2;   // wq slot; wk,wv,wg,wo follow
        const float* nlw = pass ? ff_ln_w : (const float*)d_in[18];
        const float* nlb = pass ? ff_ln_b : (const float*)d_in[19];
        ushort* Qb   = R0;
        ushort* Kb2  = pass ? R3 : R1;
        ushort* VTb  = R2;
        ushort* PVb  = R0;
        ushort* XLNn = pass ? R3 : R1;
        // q,k,v,g off one staged A (g overwrites XLN in place — blocks only touch own rows)
        qkv4_gemm<<<LL/64, 256, 0, stream>>>(XLN, wt + ws0*WS, Qb, Kb2, VTb, XLN, wp[9], SCALE, 1.f/LDIM);
        score128<<<dim3(9, HN, NCHUNK), 256, 0, stream>>>(Qb, Kb2, partialb);
        softmax_kernel<<<HN*LDIM, 64, 0, stream>>>(partialb, battnb, attn_bf);
        pvg_gemm<<<dim3(96, 3, 4), 256, 0, stream>>>(attn_bf, VTb, PVb);
        // pair_out = residual + (g .* pv)@wo + bo ; fused LN -> next xln
        mgemm64<0,2,3,1><<<dim3(1,1152), 256, 0, stream>>>(PVb, wt + (ws0+4)*WS, wp[11], XLN, P, out,
            nlw, nlb, XLNn, 128, 128, 128, 1.f, trans, trans);
        XLN = XLNn;
    }

    // FFN: out += relu(xln@w1+b1)@w2+b2  (h1 bf16 [LL][256] spans R0+R1)
    mgemm64<1,1,1,0><<<dim3(2,1152), 256, 0, stream>>>(XLN, wt_ff1, ff_b1, nullptr, nullptr, R0,
        nullptr, nullptr, nullptr, 256, 128, 128, 1.f, 0, 0);
    mgemm64<0,1,0,0><<<dim3(1,1152), 256, 0, stream>>>(R0, wt_ff2, ff_b2, nullptr, out, out,
        nullptr, nullptr, nullptr, 128, 256, 256, 1.f, 0, 0);
}

// Round 14
// 812.610 us; speedup vs baseline: 1.1442x; 1.0053x over previous
//
#include <hip/hip_runtime.h>
#include <hip/hip_bf16.h>
#include <math.h>

#define LDIM 384
#define CDIM 128
#define HN 4
#define LL (LDIM*LDIM)
#define NCHUNK 8
#define VTPLANE ((size_t)12288*384)

typedef __attribute__((ext_vector_type(8))) short bf16x8;
typedef __attribute__((ext_vector_type(4))) float f32x4;

__device__ __forceinline__ ushort f2bf(float x) {
    union { __hip_bfloat16 h; ushort u; } cv;
    cv.h = __float2bfloat16(x);
    return cv.u;
}
__device__ __forceinline__ float bf2f(ushort u) {
    union { unsigned int i; float f; } cv; cv.i = ((unsigned int)u) << 16; return cv.f;
}
__device__ __forceinline__ int swz256(int row, int cb) { return (row * 256 + cb) ^ ((row & 7) << 4); }
__device__ __forceinline__ int swz128(int row, int cb) { return (row * 128 + cb) ^ ((row & 7) << 4); }
__device__ __forceinline__ size_t trow(int row) { return (size_t)(row % LDIM) * LDIM + row / LDIM; }

// ---------------- weight prep: fp32 [K][N] -> bf16 [N][KP] (zero-padded K) ----------------
__global__ __launch_bounds__(256) void wprep_kernel(ushort* __restrict__ wt,
    const float* emb_w, const float* proj_w,
    const float* rwq, const float* rwk, const float* rwv, const float* rwg, const float* rwo,
    const float* cwq, const float* cwk, const float* cwv, const float* cwg, const float* cwo,
    const float* ffw1, const float* ffw2)
{
    int y = blockIdx.y;
    const float* src; int N, K, KP; size_t off;
    switch (y) {
        case 0:  src = emb_w;  N = 128; K = 36;  KP = 128; off = 0;         break;
        case 1:  src = proj_w; N = 128; K = 128; KP = 128; off = 16384;     break;
        case 2:  src = rwq;    N = 128; K = 128; KP = 128; off = 2*16384;   break;
        case 3:  src = rwk;    N = 128; K = 128; KP = 128; off = 3*16384;   break;
        case 4:  src = rwv;    N = 128; K = 128; KP = 128; off = 4*16384;   break;
        case 5:  src = rwg;    N = 128; K = 128; KP = 128; off = 5*16384;   break;
        case 6:  src = rwo;    N = 128; K = 128; KP = 128; off = 6*16384;   break;
        case 7:  src = cwq;    N = 128; K = 128; KP = 128; off = 7*16384;   break;
        case 8:  src = cwk;    N = 128; K = 128; KP = 128; off = 8*16384;   break;
        case 9:  src = cwv;    N = 128; K = 128; KP = 128; off = 9*16384;   break;
        case 10: src = cwg;    N = 128; K = 128; KP = 128; off = 10*16384;  break;
        case 11: src = cwo;    N = 128; K = 128; KP = 128; off = 11*16384;  break;
        case 12: src = ffw1;   N = 256; K = 128; KP = 128; off = 12*16384;  break;
        default: src = ffw2;   N = 128; K = 256; KP = 256; off = 12*16384 + 32768; break;
    }
    int e = blockIdx.x * 256 + threadIdx.x;
    if (e >= N * KP) return;
    int nn = e / KP, kp = e - nn * KP;
    float v = (kp < K) ? src[(size_t)kp * N + nn] : 0.f;
    wt[off + e] = f2bf(v);
}

// ------- LN + bf16 pack: coalesced read of src row p, write to dst row trans(p) -------
__global__ __launch_bounds__(256) void lnpack_kernel(const float* __restrict__ src,
    ushort* __restrict__ dst, const float* __restrict__ w, const float* __restrict__ b, int trans)
{
    int p = (blockIdx.x << 2) + (threadIdx.x >> 6);
    int lane = threadIdx.x & 63;
    float2 v = *(const float2*)(src + (size_t)p * CDIM + (lane << 1));
    float s  = v.x + v.y;
    float ss = v.x*v.x + v.y*v.y;
    #pragma unroll
    for (int off = 32; off; off >>= 1) { s += __shfl_xor(s, off, 64); ss += __shfl_xor(ss, off, 64); }
    float mean = s * (1.0f/CDIM);
    float var  = ss * (1.0f/CDIM) - mean*mean;
    float rstd = rsqrtf(var + 1e-5f);
    int q = trans ? ((p % LDIM) * LDIM + p / LDIM) : p;
    ushort2 o;
    o.x = f2bf((v.x - mean) * rstd * w[lane<<1]     + b[lane<<1]);
    o.y = f2bf((v.y - mean) * rstd * w[(lane<<1)+1] + b[(lane<<1)+1]);
    *(ushort2*)(dst + (size_t)q * CDIM + (lane << 1)) = o;
}

// ------- dual bias-attention, 8 lanes/row, 8 rows/wave: read 16 ch/lane coalesced, -------
// ------- 3-level shfl reduce within the 8-lane row group, write both frames. -------
__global__ __launch_bounds__(256) void battn2_kernel(const float* __restrict__ rbf,
    float* __restrict__ battn_r, float* __restrict__ battn_c,
    const float* __restrict__ rlnw, const float* __restrict__ rlnb, const float* __restrict__ rwb,
    const float* __restrict__ clnw, const float* __restrict__ clnb, const float* __restrict__ cwb)
{
    int t = threadIdx.x;
    int w = t >> 6, l = t & 63;
    int rloc = l >> 3, sl = l & 7;
    int p = (blockIdx.x << 5) + (w << 3) + rloc;
    int a = p / LDIM, b2 = p % LDIM;
    int ch0 = sl << 4;
    const float* rp = rbf + (size_t)p * CDIM + ch0;
    float4 v0 = *(const float4*)rp,       v1 = *(const float4*)(rp + 4),
           v2 = *(const float4*)(rp + 8), v3 = *(const float4*)(rp + 12);
    float x[16] = { v0.x,v0.y,v0.z,v0.w, v1.x,v1.y,v1.z,v1.w,
                    v2.x,v2.y,v2.z,v2.w, v3.x,v3.y,v3.z,v3.w };
    float s = 0.f, ss = 0.f;
    #pragma unroll
    for (int i = 0; i < 16; i++) { s += x[i]; ss += x[i]*x[i]; }
    #pragma unroll
    for (int off = 1; off < 8; off <<= 1) { s += __shfl_xor(s, off, 64); ss += __shfl_xor(ss, off, 64); }
    float mean = s * (1.f/CDIM);
    float var  = ss * (1.f/CDIM) - mean*mean;
    float rstd = rsqrtf(var + 1e-5f);
    float racc0=0.f, racc1=0.f, racc2=0.f, racc3=0.f;
    float cacc0=0.f, cacc1=0.f, cacc2=0.f, cacc3=0.f;
    #pragma unroll
    for (int i = 0; i < 16; i++) {
        int ch = ch0 + i;
        float cn = (x[i] - mean) * rstd;
        float xr = cn * rlnw[ch] + rlnb[ch];
        float xc = cn * clnw[ch] + clnb[ch];
        int q = ch * HN;
        racc0 += xr * rwb[q+0]; racc1 += xr * rwb[q+1];
        racc2 += xr * rwb[q+2]; racc3 += xr * rwb[q+3];
        cacc0 += xc * cwb[q+0]; cacc1 += xc * cwb[q+1];
        cacc2 += xc * cwb[q+2]; cacc3 += xc * cwb[q+3];
    }
    #pragma unroll
    for (int off = 1; off < 8; off <<= 1) {
        racc0 += __shfl_xor(racc0, off, 64); racc1 += __shfl_xor(racc1, off, 64);
        racc2 += __shfl_xor(racc2, off, 64); racc3 += __shfl_xor(racc3, off, 64);
        cacc0 += __shfl_xor(cacc0, off, 64); cacc1 += __shfl_xor(cacc1, off, 64);
        cacc2 += __shfl_xor(cacc2, off, 64); cacc3 += __shfl_xor(cacc3, off, 64);
    }
    if (sl == 0) {
        battn_r[((size_t)0*LDIM + b2)*LDIM + a] = racc0;
        battn_r[((size_t)1*LDIM + b2)*LDIM + a] = racc1;
        battn_r[((size_t)2*LDIM + b2)*LDIM + a] = racc2;
        battn_r[((size_t)3*LDIM + b2)*LDIM + a] = racc3;
        battn_c[((size_t)0*LDIM + a)*LDIM + b2] = cacc0;
        battn_c[((size_t)1*LDIM + a)*LDIM + b2] = cacc1;
        battn_c[((size_t)2*LDIM + a)*LDIM + b2] = cacc2;
        battn_c[((size_t)3*LDIM + a)*LDIM + b2] = cacc3;
    }
}

// ------- BK=64 128x128-tile MFMA GEMM (round-7 verified config). -------
// AMODE: 0 fp32, 1 bf16, 2 bf16 gated. OUTMODE: 0 fp32 (+res), 1 bf16, 3 fp32 w/ rtrans/otrans.
// LNOUT: fuse LN over 128 out channels (N=128, grid.x=1, OUTMODE3): writes out fp32 + xln bf16.
template<int ACT, int AMODE, int OUTMODE, int LNOUT>
__global__ __launch_bounds__(256) void mgemm64(
    const void* __restrict__ Ain, const ushort* __restrict__ Wt,
    const float* __restrict__ bias, const ushort* __restrict__ gmul,
    const float* __restrict__ res, void* __restrict__ Cout,
    const float* __restrict__ lnw2, const float* __restrict__ lnb2, ushort* __restrict__ xln,
    int N, int KP, int lda, float alpha, int rtrans, int otrans)
{
    __shared__ ushort As[128*64];
    __shared__ ushort Ws[128*64];
    int t = threadIdx.x, l = t & 63, wv = t >> 6;
    int m0 = blockIdx.y << 7, n0 = blockIdx.x << 7;
    int wm = (wv >> 1) << 6, wn = (wv & 1) << 6;
    int sr = t >> 1;            // staging row
    int sh = (t & 1) << 5;      // k offset (shorts)
    f32x4 acc[4][4] = {};
    for (int k0 = 0; k0 < KP; k0 += 64) {
        if (k0) __syncthreads();
        if (AMODE == 1) {
            const ushort* ap = (const ushort*)Ain + (size_t)(m0 + sr) * lda + k0 + sh;
            #pragma unroll
            for (int u = 0; u < 4; u++)
                *(int4*)((char*)As + swz128(sr, (sh << 1) + (u << 4))) = *(const int4*)(ap + (u << 3));
        } else if (AMODE == 2) {
            const ushort* ap = (const ushort*)Ain + (size_t)(m0 + sr) * lda + k0 + sh;
            const ushort* gp = gmul + (size_t)(m0 + sr) * lda + k0 + sh;
            #pragma unroll
            for (int u = 0; u < 4; u++) {
                int4 av = *(const int4*)(ap + (u << 3));
                int4 gv = *(const int4*)(gp + (u << 3));
                ushort* au = (ushort*)&av; ushort* gu = (ushort*)&gv;
                short v8[8];
                #pragma unroll
                for (int e = 0; e < 8; e++) v8[e] = (short)f2bf(bf2f(au[e]) * bf2f(gu[e]));
                *(int4*)((char*)As + swz128(sr, (sh << 1) + (u << 4))) = *(int4*)v8;
            }
        } else {
            const float* ap = (const float*)Ain + (size_t)(m0 + sr) * lda;
            #pragma unroll
            for (int u = 0; u < 4; u++) {
                short v8[8];
                #pragma unroll
                for (int e = 0; e < 8; e++) {
                    int c = k0 + sh + (u << 3) + e;
                    v8[e] = (short)f2bf((c < lda) ? ap[c] : 0.f);
                }
                *(int4*)((char*)As + swz128(sr, (sh << 1) + (u << 4))) = *(int4*)v8;
            }
        }
        {
            const ushort* wp2 = Wt + (size_t)(n0 + sr) * KP + k0 + sh;
            #pragma unroll
            for (int u = 0; u < 4; u++)
                *(int4*)((char*)Ws + swz128(sr, (sh << 1) + (u << 4))) = *(const int4*)(wp2 + (u << 3));
        }
        __syncthreads();
        #pragma unroll
        for (int ks = 0; ks < 2; ks++) {
            int kb = (ks << 6) + ((l >> 4) << 4);
            bf16x8 a[4], b[4];
            #pragma unroll
            for (int x = 0; x < 4; x++) {
                a[x] = *(const bf16x8*)((char*)As + swz128(wm + (x << 4) + (l & 15), kb));
                b[x] = *(const bf16x8*)((char*)Ws + swz128(wn + (x << 4) + (l & 15), kb));
            }
            #pragma unroll
            for (int i = 0; i < 4; i++)
            #pragma unroll
            for (int j = 0; j < 4; j++)
                acc[i][j] = __builtin_amdgcn_mfma_f32_16x16x32_bf16(a[i], b[j], acc[i][j], 0, 0, 0);
        }
    }
    if (LNOUT) {
        #pragma unroll
        for (int mf = 0; mf < 4; mf++)
        #pragma unroll
        for (int nf = 0; nf < 4; nf++) {
            int col  = wn + (nf << 4) + (l & 15);
            int row0 = m0 + wm + (mf << 4) + ((l >> 4) << 2);
            float bb = bias ? bias[col] : 0.f;
            #pragma unroll
            for (int r = 0; r < 4; r++) {
                int row = row0 + r;
                size_t rrow = rtrans ? trow(row) : (size_t)row;
                acc[mf][nf][r] = acc[mf][nf][r] * alpha + bb + (res ? res[rrow * CDIM + col] : 0.f);
            }
        }
        float ps[4][4], pq[4][4];
        #pragma unroll
        for (int mf = 0; mf < 4; mf++)
        #pragma unroll
        for (int r = 0; r < 4; r++) {
            float s = 0.f, q = 0.f;
            #pragma unroll
            for (int nf = 0; nf < 4; nf++) { float v = acc[mf][nf][r]; s += v; q += v * v; }
            ps[mf][r] = s; pq[mf][r] = q;
        }
        #pragma unroll
        for (int off = 1; off < 16; off <<= 1)
        #pragma unroll
        for (int mf = 0; mf < 4; mf++)
        #pragma unroll
        for (int r = 0; r < 4; r++) {
            ps[mf][r] += __shfl_xor(ps[mf][r], off, 64);
            pq[mf][r] += __shfl_xor(pq[mf][r], off, 64);
        }
        __syncthreads();
        float* lnbuf = (float*)As;       // [2][128][2]
        if ((l & 15) == 0) {
            #pragma unroll
            for (int mf = 0; mf < 4; mf++)
            #pragma unroll
            for (int r = 0; r < 4; r++) {
                int rl = wm + (mf << 4) + ((l >> 4) << 2) + r;
                lnbuf[(((wv & 1) << 7) + rl) * 2 + 0] = ps[mf][r];
                lnbuf[(((wv & 1) << 7) + rl) * 2 + 1] = pq[mf][r];
            }
        }
        __syncthreads();
        #pragma unroll
        for (int mf = 0; mf < 4; mf++)
        #pragma unroll
        for (int nf = 0; nf < 4; nf++) {
            int col  = wn + (nf << 4) + (l & 15);
            int row0 = m0 + wm + (mf << 4) + ((l >> 4) << 2);
            float lw = lnw2[col], lb = lnb2[col];
            #pragma unroll
            for (int r = 0; r < 4; r++) {
                int row = row0 + r;
                int rl  = wm + (mf << 4) + ((l >> 4) << 2) + r;
                float s  = lnbuf[rl * 2 + 0] + lnbuf[(256 + rl * 2) + 0];
                float q  = lnbuf[rl * 2 + 1] + lnbuf[(256 + rl * 2) + 1];
                float mean = s * (1.f/CDIM);
                float var  = q * (1.f/CDIM) - mean * mean;
                float rstd = rsqrtf(var + 1e-5f);
                float o = acc[mf][nf][r];
                size_t orow = otrans ? trow(row) : (size_t)row;
                ((float*)Cout)[orow * CDIM + col] = o;
                xln[orow * CDIM + col] = f2bf((o - mean) * rstd * lw + lb);
            }
        }
    } else {
        #pragma unroll
        for (int mf = 0; mf < 4; mf++)
        #pragma unroll
        for (int nf = 0; nf < 4; nf++) {
            int col  = n0 + wn + (nf << 4) + (l & 15);
            int row0 = m0 + wm + (mf << 4) + ((l >> 4) << 2);
            float bb = bias ? bias[col] : 0.f;
            #pragma unroll
            for (int r = 0; r < 4; r++) {
                int row = row0 + r;
                float v = acc[mf][nf][r] * alpha + bb;
                if (ACT == 1) v = fmaxf(v, 0.f);
                if (ACT == 2) v = 1.f / (1.f + __expf(-v));
                if (OUTMODE == 0) {
                    float o = v + (res ? res[(size_t)row * N + col] : 0.f);
                    ((float*)Cout)[(size_t)row * N + col] = o;
                } else if (OUTMODE == 1) {
                    ((ushort*)Cout)[(size_t)row * N + col] = f2bf(v);
                } else {
                    size_t orow = otrans ? trow(row) : (size_t)row;
                    size_t rrow = rtrans ? trow(row) : (size_t)row;
                    float o = v + (res ? res[rrow * N + col] : 0.f);
                    ((float*)Cout)[orow * N + col] = o;
                }
            }
        }
    }
}

// ------- q,k,v,g: M=64 tile (As 16KB + Ws 32KB = 48KB -> 3 blocks/CU), 2304 blocks -------
__global__ __launch_bounds__(256) void qkv4_gemm(
    const ushort* __restrict__ A, const ushort* __restrict__ wt4,
    ushort* __restrict__ qo, ushort* __restrict__ ko, ushort* __restrict__ vt,
    ushort* __restrict__ go, const float* __restrict__ bg,
    float scale_q, float scale_k)
{
    __shared__ ushort As[64*128];    // 16 KB
    __shared__ ushort Ws[128*128];   // 32 KB
    int t = threadIdx.x, l = t & 63, wv = t >> 6;
    int m0 = blockIdx.x << 6;
    int wm = (wv >> 1) << 5;         // 0 / 32
    int wn = (wv & 1) << 6;          // 0 / 64
    {
        int sr = t >> 2, scb = (t & 3) << 6;
        const ushort* ap = A + (size_t)(m0 + sr) * CDIM + (scb >> 1);
        #pragma unroll
        for (int u = 0; u < 4; u++)
            *(int4*)((char*)As + swz256(sr, scb + (u << 4))) = *(const int4*)(ap + (u << 3));
    }
    for (int comp = 0; comp < 4; comp++) {
        if (comp) __syncthreads();
        {
            int sr = t >> 1, scb = (t & 1) << 7;
            const ushort* wp2 = wt4 + (size_t)comp * 16384 + (size_t)sr * CDIM + (scb >> 1);
            #pragma unroll
            for (int u = 0; u < 8; u++)
                *(int4*)((char*)Ws + swz256(sr, scb + (u << 4))) = *(const int4*)(wp2 + (u << 3));
        }
        __syncthreads();
        f32x4 acc[2][4] = {};
        #pragma unroll
        for (int ks = 0; ks < 4; ks++) {
            int kb = (ks << 6) + ((l >> 4) << 4);
            bf16x8 a[2], b[4];
            #pragma unroll
            for (int x = 0; x < 2; x++)
                a[x] = *(const bf16x8*)((char*)As + swz256(wm + (x << 4) + (l & 15), kb));
            #pragma unroll
            for (int x = 0; x < 4; x++)
                b[x] = *(const bf16x8*)((char*)Ws + swz256(wn + (x << 4) + (l & 15), kb));
            #pragma unroll
            for (int i = 0; i < 2; i++)
            #pragma unroll
            for (int j = 0; j < 4; j++)
                acc[i][j] = __builtin_amdgcn_mfma_f32_16x16x32_bf16(a[i], b[j], acc[i][j], 0, 0, 0);
        }
        #pragma unroll
        for (int mf = 0; mf < 2; mf++)
        #pragma unroll
        for (int nf = 0; nf < 4; nf++) {
            int col  = wn + (nf << 4) + (l & 15);
            int row0 = m0 + wm + (mf << 4) + ((l >> 4) << 2);
            if (comp == 0) {
                #pragma unroll
                for (int r = 0; r < 4; r++)
                    qo[(size_t)(row0 + r) * CDIM + col] = f2bf(acc[mf][nf][r] * scale_q);
            } else if (comp == 1) {
                #pragma unroll
                for (int r = 0; r < 4; r++)
                    ko[(size_t)(row0 + r) * CDIM + col] = f2bf(acc[mf][nf][r] * scale_k);
            } else if (comp == 2) {
                ushort4 pk;
                #pragma unroll
                for (int r = 0; r < 4; r++) ((ushort*)&pk)[r] = f2bf(acc[mf][nf][r]);
                int n = row0 / LDIM, j = row0 % LDIM;   // 64-row tiles never cross n
                *(ushort4*)&vt[((size_t)(col >> 5) * 12288 + (size_t)n * 32 + (col & 31)) * 384 + j] = pk;
            } else {
                float bb = bg[col];
                #pragma unroll
                for (int r = 0; r < 4; r++) {
                    float v = acc[mf][nf][r] + bb;
                    go[(size_t)(row0 + r) * CDIM + col] = f2bf(1.f / (1.f + __expf(-v)));
                }
            }
        }
    }
}

// ------- tied scores (verified round-7 3D grid): partial[cz,h,i,j] -------
__global__ __launch_bounds__(256) void score128(const ushort* __restrict__ Q,
    const ushort* __restrict__ Kb, float* __restrict__ partial)
{
    __shared__ ushort As[128*128];
    __shared__ ushort Bs[128*128];
    int t = threadIdx.x, l = t & 63, wv = t >> 6;
    int ti = blockIdx.x / 3, tj = blockIdx.x % 3;
    int h = blockIdx.y, cz = blockIdx.z;
    int i0 = ti << 7, j0 = tj << 7;
    int wm = (wv >> 1) << 6, wn = (wv & 1) << 6;
    int sr = t >> 1, half = t & 1;
    f32x4 acc[4][4] = {};
    for (int it = 0; it < 12; it++) {
        if (it) __syncthreads();
        int nb = cz * 48 + (it << 2);
        #pragma unroll
        for (int e = 0; e < 2; e++) {
            int nq = (half << 1) + e;
            const ushort* qp = Q  + ((size_t)(nb + nq) * LDIM + i0 + sr) * CDIM + (h << 5);
            const ushort* kp = Kb + ((size_t)(nb + nq) * LDIM + j0 + sr) * CDIM + (h << 5);
            *(int4*)((char*)As + swz256(sr, (nq << 6) +  0)) = *(const int4*)qp;
            *(int4*)((char*)As + swz256(sr, (nq << 6) + 16)) = *(const int4*)(qp + 8);
            *(int4*)((char*)As + swz256(sr, (nq << 6) + 32)) = *(const int4*)(qp + 16);
            *(int4*)((char*)As + swz256(sr, (nq << 6) + 48)) = *(const int4*)(qp + 24);
            *(int4*)((char*)Bs + swz256(sr, (nq << 6) +  0)) = *(const int4*)kp;
            *(int4*)((char*)Bs + swz256(sr, (nq << 6) + 16)) = *(const int4*)(kp + 8);
            *(int4*)((char*)Bs + swz256(sr, (nq << 6) + 32)) = *(const int4*)(kp + 16);
            *(int4*)((char*)Bs + swz256(sr, (nq << 6) + 48)) = *(const int4*)(kp + 24);
        }
        __syncthreads();
        #pragma unroll
        for (int ks = 0; ks < 4; ks++) {
            int kb = (ks << 6) + ((l >> 4) << 4);
            bf16x8 a[4], b[4];
            #pragma unroll
            for (int x = 0; x < 4; x++) {
                a[x] = *(const bf16x8*)((char*)As + swz256(wm + (x << 4) + (l & 15), kb));
                b[x] = *(const bf16x8*)((char*)Bs + swz256(wn + (x << 4) + (l & 15), kb));
            }
            #pragma unroll
            for (int i = 0; i < 4; i++)
            #pragma unroll
            for (int j = 0; j < 4; j++)
                acc[i][j] = __builtin_amdgcn_mfma_f32_16x16x32_bf16(a[i], b[j], acc[i][j], 0, 0, 0);
        }
    }
    #pragma unroll
    for (int mf = 0; mf < 4; mf++)
    #pragma unroll
    for (int nf = 0; nf < 4; nf++) {
        int j = j0 + wn + (nf << 4) + (l & 15);
        int i = i0 + wm + (mf << 4) + ((l >> 4) << 2);
        #pragma unroll
        for (int r = 0; r < 4; r++)
            partial[((size_t)(cz*HN + h)*LDIM + i + r)*LDIM + j] = acc[mf][nf][r];
    }
}

// ---------------- softmax over j (chunk reduce + bias) -> bf16 ----------------
__global__ __launch_bounds__(64) void softmax_kernel(
    const float* __restrict__ partial, const float* __restrict__ battn, ushort* __restrict__ attn)
{
    int hi = blockIdx.x;
    int l = threadIdx.x;
    float s[6];
    #pragma unroll
    for (int u = 0; u < 6; u++) {
        size_t idx = (size_t)hi * LDIM + l + (u << 6);
        float v = battn[idx];
        #pragma unroll
        for (int c = 0; c < NCHUNK; c++) v += partial[(size_t)c * HN * LL + idx];
        s[u] = v;
    }
    float m = s[0];
    #pragma unroll
    for (int u = 1; u < 6; u++) m = fmaxf(m, s[u]);
    #pragma unroll
    for (int off = 32; off; off >>= 1) m = fmaxf(m, __shfl_xor(m, off, 64));
    float sum = 0.f;
    #pragma unroll
    for (int u = 0; u < 6; u++) { s[u] = __expf(s[u] - m); sum += s[u]; }
    #pragma unroll
    for (int off = 32; off; off >>= 1) sum += __shfl_xor(sum, off, 64);
    float inv = 1.f / sum;
    #pragma unroll
    for (int u = 0; u < 6; u++) attn[(size_t)hi * LDIM + l + (u << 6)] = f2bf(s[u] * inv);
}

// ------- PV per-head GEMM (BK=64): pvout[(n,i),h*32+d] -------
__global__ __launch_bounds__(256) void pvg_gemm(const ushort* __restrict__ attn,
    const ushort* __restrict__ vt, ushort* __restrict__ pvout)
{
    __shared__ ushort As[128*64];
    __shared__ ushort Ws[128*64];
    int t = threadIdx.x, l = t & 63, wv = t >> 6;
    int n0 = blockIdx.x << 7;
    int i0 = blockIdx.y << 7;
    int h  = blockIdx.z;
    const ushort* abase = attn + (size_t)h * LL;
    const ushort* bbase = vt + (size_t)h * VTPLANE;
    int wm = (wv >> 1) << 6, wn = (wv & 1) << 6;
    int sr = t >> 1, sh = (t & 1) << 5;
    f32x4 acc[4][4] = {};
    for (int k0 = 0; k0 < LDIM; k0 += 64) {
        if (k0) __syncthreads();
        {
            const ushort* ap = abase + (size_t)(i0 + sr) * LDIM + k0 + sh;
            const ushort* bp = bbase + (size_t)(n0 + sr) * LDIM + k0 + sh;
            #pragma unroll
            for (int u = 0; u < 4; u++) {
                *(int4*)((char*)As + swz128(sr, (sh << 1) + (u << 4))) = *(const int4*)(ap + (u << 3));
                *(int4*)((char*)Ws + swz128(sr, (sh << 1) + (u << 4))) = *(const int4*)(bp + (u << 3));
            }
        }
        __syncthreads();
        #pragma unroll
        for (int ks = 0; ks < 2; ks++) {
            int kb = (ks << 6) + ((l >> 4) << 4);
            bf16x8 a[4], b[4];
            #pragma unroll
            for (int x = 0; x < 4; x++) {
                a[x] = *(const bf16x8*)((char*)As + swz128(wm + (x << 4) + (l & 15), kb));
                b[x] = *(const bf16x8*)((char*)Ws + swz128(wn + (x << 4) + (l & 15), kb));
            }
            #pragma unroll
            for (int i = 0; i < 4; i++)
            #pragma unroll
            for (int j = 0; j < 4; j++)
                acc[i][j] = __builtin_amdgcn_mfma_f32_16x16x32_bf16(a[i], b[j], acc[i][j], 0, 0, 0);
        }
    }
    #pragma unroll
    for (int mf = 0; mf < 4; mf++)
    #pragma unroll
    for (int nf = 0; nf < 4; nf++) {
        int col  = n0 + wn + (nf << 4) + (l & 15);
        int row0 = i0 + wm + (mf << 4) + ((l >> 4) << 2);
        int n = col >> 5, d = col & 31;
        #pragma unroll
        for (int r = 0; r < 4; r++) {
            int i = row0 + r;
            pvout[((size_t)n * LDIM + i) * CDIM + (h << 5) + d] = f2bf(acc[mf][nf][r]);
        }
    }
}

extern "C" void kernel_launch(void* const* d_in, const int* in_sizes, int n_in,
                              void* d_out, int out_size, void* d_ws, size_t ws_size,
                              hipStream_t stream)
{
    const float* pair     = (const float*)d_in[0];
    const float* rbf_feat = (const float*)d_in[1];
    const float* emb_b    = (const float*)d_in[3];
    const float* proj_b   = (const float*)d_in[5];
    const float* ff_ln_w  = (const float*)d_in[30];
    const float* ff_ln_b  = (const float*)d_in[31];
    const float* ff_b1    = (const float*)d_in[33];
    const float* ff_b2    = (const float*)d_in[35];
    float* out = (float*)d_out;

    ushort* R0 = (ushort*)d_ws;
    ushort* R1 = R0 + (size_t)LL*CDIM;
    ushort* R2 = R1 + (size_t)LL*CDIM;
    ushort* R3 = R2 + (size_t)LL*CDIM;
    float*  partialb = (float*)(R3 + (size_t)LL*CDIM);
    float*  battn_r  = partialb + (size_t)NCHUNK*HN*LL;
    float*  battn_c  = battn_r  + (size_t)HN*LL;
    ushort* attn_bf  = (ushort*)(battn_c + (size_t)HN*LL);
    ushort* wt       = attn_bf + (size_t)HN*LL;

    size_t need_bytes = (size_t)4*LL*CDIM*2 + ((size_t)NCHUNK*HN*LL + 2*(size_t)HN*LL)*4
                      + (size_t)HN*LL*2 + (size_t)262144*2;
    if (ws_size < need_bytes) return;

    const size_t WS = 16384;
    ushort* wt_emb  = wt;
    ushort* wt_proj = wt + WS;
    ushort* wt_ff1  = wt + 12*WS;
    ushort* wt_ff2  = wt + 12*WS + 32768;

    const float SCALE = 0.17677669529663687f;  // 32^-0.5

    wprep_kernel<<<dim3(128, 14), 256, 0, stream>>>(wt,
        (const float*)d_in[2], (const float*)d_in[4],
        (const float*)d_in[10], (const float*)d_in[11], (const float*)d_in[12],
        (const float*)d_in[14], (const float*)d_in[16],
        (const float*)d_in[22], (const float*)d_in[23], (const float*)d_in[24],
        (const float*)d_in[26], (const float*)d_in[28],
        (const float*)d_in[32], (const float*)d_in[34]);

    // rbf = relu(rbf_feat@emb+eb)@proj+pb : hidden bf16 -> R3; rbf fp32 spans R0+R1
    mgemm64<1,0,1,0><<<dim3(1,1152), 256, 0, stream>>>(rbf_feat, wt_emb, emb_b, nullptr, nullptr, R3,
        nullptr, nullptr, nullptr, 128, 128, 36, 1.f, 0, 0);
    mgemm64<0,1,0,0><<<dim3(1,1152), 256, 0, stream>>>(R3, wt_proj, proj_b, nullptr, nullptr, (float*)R0,
        nullptr, nullptr, nullptr, 128, 128, 128, 1.f, 0, 0);
    // both frames' pairwise bias in ONE pass over rbf (8 lanes/row)
    battn2_kernel<<<LL/32, 256, 0, stream>>>((const float*)R0, battn_r, battn_c,
        (const float*)d_in[8],  (const float*)d_in[9],  (const float*)d_in[13],
        (const float*)d_in[20], (const float*)d_in[21], (const float*)d_in[25]);

    // initial row-pass xln (transposed frame) -> R3
    lnpack_kernel<<<LL/4, 256, 0, stream>>>(pair, R3, (const float*)d_in[6], (const float*)d_in[7], 1);

    ushort* XLN = R3;
    for (int pass = 0; pass < 2; pass++) {
        const float* const* wp = (const float* const*)(d_in + (pass ? 18 : 6));
        int trans = pass ? 0 : 1;
        const float* P = pass ? (const float*)out : pair;
        const float* battnb = pass ? battn_c : battn_r;
        int ws0 = pass ? 7 : 2;   // wq slot; wk,wv,wg,wo follow
        const float* nlw = pass ? ff_ln_w : (const float*)d_in[18];
        const float* nlb = pass ? ff_ln_b : (const float*)d_in[19];
        ushort* Qb   = R0;
        ushort* Kb2  = pass ? R3 : R1;
        ushort* VTb  = R2;
        ushort* PVb  = R0;
        ushort* XLNn = pass ? R3 : R1;
        // q,k,v,g off one staged A (g overwrites XLN in place — blocks only touch own rows)
        qkv4_gemm<<<LL/64, 256, 0, stream>>>(XLN, wt + ws0*WS, Qb, Kb2, VTb, XLN, wp[9], SCALE, 1.f/LDIM);
        score128<<<dim3(9, HN, NCHUNK), 256, 0, stream>>>(Qb, Kb2, partialb);
        softmax_kernel<<<HN*LDIM, 64, 0, stream>>>(partialb, battnb, attn_bf);
        pvg_gemm<<<dim3(96, 3, 4), 256, 0, stream>>>(attn_bf, VTb, PVb);
        // pair_out = residual + (g .* pv)@wo + bo ; fused LN -> next xln
        mgemm64<0,2,3,1><<<dim3(1,1152), 256, 0, stream>>>(PVb, wt + (ws0+4)*WS, wp[11], XLN, P, out,
            nlw, nlb, XLNn, 128, 128, 128, 1.f, trans, trans);
        XLN = XLNn;
    }

    // FFN: out += relu(xln@w1+b1)@w2+b2  (h1 bf16 [LL][256] spans R0+R1)
    mgemm64<1,1,1,0><<<dim3(2,1152), 256, 0, stream>>>(XLN, wt_ff1, ff_b1, nullptr, nullptr, R0,
        nullptr, nullptr, nullptr, 256, 128, 128, 1.f, 0, 0);
    mgemm64<0,1,0,0><<<dim3(1,1152), 256, 0, stream>>>(R0, wt_ff2, ff_b2, nullptr, out, out,
        nullptr, nullptr, nullptr, 128, 256, 256, 1.f, 0, 0);
}

// Round 15
// 759.677 us; speedup vs baseline: 1.2239x; 1.0697x over previous
//
#include <hip/hip_runtime.h>
#include <hip/hip_bf16.h>
#include <math.h>

#define LDIM 384
#define CDIM 128
#define HN 4
#define LL (LDIM*LDIM)
#define NCHUNK 8
#define VTPLANE ((size_t)12288*384)

typedef __attribute__((ext_vector_type(8))) short bf16x8;
typedef __attribute__((ext_vector_type(4))) float f32x4;

__device__ __forceinline__ ushort f2bf(float x) {
    union { __hip_bfloat16 h; ushort u; } cv;
    cv.h = __float2bfloat16(x);
    return cv.u;
}
__device__ __forceinline__ float bf2f(ushort u) {
    union { unsigned int i; float f; } cv; cv.i = ((unsigned int)u) << 16; return cv.f;
}
__device__ __forceinline__ int swz256(int row, int cb) { return (row * 256 + cb) ^ ((row & 7) << 4); }
__device__ __forceinline__ int swz128(int row, int cb) { return (row * 128 + cb) ^ ((row & 7) << 4); }
__device__ __forceinline__ size_t trow(int row) { return (size_t)(row % LDIM) * LDIM + row / LDIM; }

// ---------------- weight prep: fp32 [K][N] -> bf16 [N][KP] (zero-padded K) ----------------
__global__ __launch_bounds__(256) void wprep_kernel(ushort* __restrict__ wt,
    const float* emb_w, const float* proj_w,
    const float* rwq, const float* rwk, const float* rwv, const float* rwg, const float* rwo,
    const float* cwq, const float* cwk, const float* cwv, const float* cwg, const float* cwo,
    const float* ffw1, const float* ffw2)
{
    int y = blockIdx.y;
    const float* src; int N, K, KP; size_t off;
    switch (y) {
        case 0:  src = emb_w;  N = 128; K = 36;  KP = 128; off = 0;         break;
        case 1:  src = proj_w; N = 128; K = 128; KP = 128; off = 16384;     break;
        case 2:  src = rwq;    N = 128; K = 128; KP = 128; off = 2*16384;   break;
        case 3:  src = rwk;    N = 128; K = 128; KP = 128; off = 3*16384;   break;
        case 4:  src = rwv;    N = 128; K = 128; KP = 128; off = 4*16384;   break;
        case 5:  src = rwg;    N = 128; K = 128; KP = 128; off = 5*16384;   break;
        case 6:  src = rwo;    N = 128; K = 128; KP = 128; off = 6*16384;   break;
        case 7:  src = cwq;    N = 128; K = 128; KP = 128; off = 7*16384;   break;
        case 8:  src = cwk;    N = 128; K = 128; KP = 128; off = 8*16384;   break;
        case 9:  src = cwv;    N = 128; K = 128; KP = 128; off = 9*16384;   break;
        case 10: src = cwg;    N = 128; K = 128; KP = 128; off = 10*16384;  break;
        case 11: src = cwo;    N = 128; K = 128; KP = 128; off = 11*16384;  break;
        case 12: src = ffw1;   N = 256; K = 128; KP = 128; off = 12*16384;  break;
        default: src = ffw2;   N = 128; K = 256; KP = 256; off = 12*16384 + 32768; break;
    }
    int e = blockIdx.x * 256 + threadIdx.x;
    if (e >= N * KP) return;
    int nn = e / KP, kp = e - nn * KP;
    float v = (kp < K) ? src[(size_t)kp * N + nn] : 0.f;
    wt[off + e] = f2bf(v);
}

// ------- LN + bf16 pack: coalesced read of src row p, write to dst row trans(p) -------
__global__ __launch_bounds__(256) void lnpack_kernel(const float* __restrict__ src,
    ushort* __restrict__ dst, const float* __restrict__ w, const float* __restrict__ b, int trans)
{
    int p = (blockIdx.x << 2) + (threadIdx.x >> 6);
    int lane = threadIdx.x & 63;
    float2 v = *(const float2*)(src + (size_t)p * CDIM + (lane << 1));
    float s  = v.x + v.y;
    float ss = v.x*v.x + v.y*v.y;
    #pragma unroll
    for (int off = 32; off; off >>= 1) { s += __shfl_xor(s, off, 64); ss += __shfl_xor(ss, off, 64); }
    float mean = s * (1.0f/CDIM);
    float var  = ss * (1.0f/CDIM) - mean*mean;
    float rstd = rsqrtf(var + 1e-5f);
    int q = trans ? ((p % LDIM) * LDIM + p / LDIM) : p;
    ushort2 o;
    o.x = f2bf((v.x - mean) * rstd * w[lane<<1]     + b[lane<<1]);
    o.y = f2bf((v.y - mean) * rstd * w[(lane<<1)+1] + b[(lane<<1)+1]);
    *(ushort2*)(dst + (size_t)q * CDIM + (lane << 1)) = o;
}

// ------- fused proj GEMM + dual battn: C (=rbf) never materialized. -------
// A bf16 [LL][128], Wt bf16 [128][128]; per row: LN stats -> two affines -> 8 head-dots.
__global__ __launch_bounds__(256) void proj_battn_gemm(
    const ushort* __restrict__ A, const ushort* __restrict__ Wt, const float* __restrict__ pb,
    const float* __restrict__ rlnw, const float* __restrict__ rlnb, const float* __restrict__ rwb,
    const float* __restrict__ clnw, const float* __restrict__ clnb, const float* __restrict__ cwb,
    float* __restrict__ battn_r, float* __restrict__ battn_c)
{
    __shared__ ushort As[128*64];
    __shared__ ushort Ws[128*64];
    int t = threadIdx.x, l = t & 63, wv = t >> 6;
    int m0 = blockIdx.x << 7;
    int wm = (wv >> 1) << 6, wn = (wv & 1) << 6;
    int sr = t >> 1, sh = (t & 1) << 5;
    f32x4 acc[4][4] = {};
    for (int k0 = 0; k0 < 128; k0 += 64) {
        if (k0) __syncthreads();
        const ushort* ap = A + (size_t)(m0 + sr) * CDIM + k0 + sh;
        #pragma unroll
        for (int u = 0; u < 4; u++)
            *(int4*)((char*)As + swz128(sr, (sh << 1) + (u << 4))) = *(const int4*)(ap + (u << 3));
        const ushort* wp2 = Wt + (size_t)sr * CDIM + k0 + sh;
        #pragma unroll
        for (int u = 0; u < 4; u++)
            *(int4*)((char*)Ws + swz128(sr, (sh << 1) + (u << 4))) = *(const int4*)(wp2 + (u << 3));
        __syncthreads();
        #pragma unroll
        for (int ks = 0; ks < 2; ks++) {
            int kb = (ks << 6) + ((l >> 4) << 4);
            bf16x8 a[4], b[4];
            #pragma unroll
            for (int x = 0; x < 4; x++) {
                a[x] = *(const bf16x8*)((char*)As + swz128(wm + (x << 4) + (l & 15), kb));
                b[x] = *(const bf16x8*)((char*)Ws + swz128(wn + (x << 4) + (l & 15), kb));
            }
            #pragma unroll
            for (int i = 0; i < 4; i++)
            #pragma unroll
            for (int j = 0; j < 4; j++)
                acc[i][j] = __builtin_amdgcn_mfma_f32_16x16x32_bf16(a[i], b[j], acc[i][j], 0, 0, 0);
        }
    }
    int lc = l & 15, lr = l >> 4;
    // per-lane column tables (cols fixed across rows)
    float pbv[4], rlw[4], rlb[4], clw[4], clb[4];
    float4 rw4[4], cw4[4];
    #pragma unroll
    for (int nf = 0; nf < 4; nf++) {
        int col = wn + (nf << 4) + lc;
        pbv[nf] = pb[col];
        rlw[nf] = rlnw[col]; rlb[nf] = rlnb[col];
        clw[nf] = clnw[col]; clb[nf] = clnb[col];
        rw4[nf] = *(const float4*)&rwb[col * HN];
        cw4[nf] = *(const float4*)&cwb[col * HN];
    }
    float* buf  = (float*)Ws;      // stats: [2][128][2] = 512 floats
    float* dbuf = buf + 512;       // dots:  [128][8]    = 1024 floats
    __syncthreads();
    #pragma unroll
    for (int mf = 0; mf < 4; mf++) {
        float v[4][4];
        #pragma unroll
        for (int r = 0; r < 4; r++)
        #pragma unroll
        for (int nf = 0; nf < 4; nf++)
            v[r][nf] = acc[mf][nf][r] + pbv[nf];
        // stats over this wave's 64-col half
        float s[4], q[4];
        #pragma unroll
        for (int r = 0; r < 4; r++) {
            float a0 = 0.f, a1 = 0.f;
            #pragma unroll
            for (int nf = 0; nf < 4; nf++) { a0 += v[r][nf]; a1 += v[r][nf]*v[r][nf]; }
            s[r] = a0; q[r] = a1;
        }
        #pragma unroll
        for (int off = 1; off < 16; off <<= 1)
        #pragma unroll
        for (int r = 0; r < 4; r++) {
            s[r] += __shfl_xor(s[r], off, 64);
            q[r] += __shfl_xor(q[r], off, 64);
        }
        if (lc == 0) {
            #pragma unroll
            for (int r = 0; r < 4; r++) {
                int rl = wm + (mf << 4) + (lr << 2) + r;
                buf[(((wv & 1) << 7) + rl) * 2 + 0] = s[r];
                buf[(((wv & 1) << 7) + rl) * 2 + 1] = q[r];
            }
        }
        __syncthreads();
        float p[4][8];
        #pragma unroll
        for (int r = 0; r < 4; r++) {
            int rl = wm + (mf << 4) + (lr << 2) + r;
            float S = buf[rl * 2 + 0] + buf[(256 + rl * 2) + 0];
            float Q = buf[rl * 2 + 1] + buf[(256 + rl * 2) + 1];
            float mean = S * (1.f/CDIM);
            float var  = Q * (1.f/CDIM) - mean * mean;
            float rstd = rsqrtf(var + 1e-5f);
            float p0=0.f,p1=0.f,p2=0.f,p3=0.f,p4=0.f,p5=0.f,p6=0.f,p7=0.f;
            #pragma unroll
            for (int nf = 0; nf < 4; nf++) {
                float cn = (v[r][nf] - mean) * rstd;
                float xr = cn * rlw[nf] + rlb[nf];
                float xc = cn * clw[nf] + clb[nf];
                p0 += xr * rw4[nf].x; p1 += xr * rw4[nf].y;
                p2 += xr * rw4[nf].z; p3 += xr * rw4[nf].w;
                p4 += xc * cw4[nf].x; p5 += xc * cw4[nf].y;
                p6 += xc * cw4[nf].z; p7 += xc * cw4[nf].w;
            }
            p[r][0]=p0; p[r][1]=p1; p[r][2]=p2; p[r][3]=p3;
            p[r][4]=p4; p[r][5]=p5; p[r][6]=p6; p[r][7]=p7;
        }
        #pragma unroll
        for (int off = 1; off < 16; off <<= 1)
        #pragma unroll
        for (int r = 0; r < 4; r++)
        #pragma unroll
        for (int i = 0; i < 8; i++)
            p[r][i] += __shfl_xor(p[r][i], off, 64);
        if (wn == 0 && lc == 0) {
            #pragma unroll
            for (int r = 0; r < 4; r++) {
                int rl = wm + (mf << 4) + (lr << 2) + r;
                #pragma unroll
                for (int i = 0; i < 8; i++) dbuf[rl * 8 + i] = p[r][i];
            }
        }
        __syncthreads();
        if (wn == 64 && lc == 0) {
            #pragma unroll
            for (int r = 0; r < 4; r++) {
                int rl = wm + (mf << 4) + (lr << 2) + r;
                int rowg = m0 + rl;
                int a = rowg / LDIM, b2 = rowg % LDIM;
                #pragma unroll
                for (int h = 0; h < HN; h++) {
                    battn_r[((size_t)h*LDIM + b2)*LDIM + a]  = p[r][h]   + dbuf[rl*8 + h];
                    battn_c[((size_t)h*LDIM + a)*LDIM + b2]  = p[r][4+h] + dbuf[rl*8 + 4 + h];
                }
            }
        }
    }
}

// ------- BK=64 128x128-tile MFMA GEMM (round-7 verified config). -------
template<int ACT, int AMODE, int OUTMODE, int LNOUT>
__global__ __launch_bounds__(256) void mgemm64(
    const void* __restrict__ Ain, const ushort* __restrict__ Wt,
    const float* __restrict__ bias, const ushort* __restrict__ gmul,
    const float* __restrict__ res, void* __restrict__ Cout,
    const float* __restrict__ lnw2, const float* __restrict__ lnb2, ushort* __restrict__ xln,
    int N, int KP, int lda, float alpha, int rtrans, int otrans)
{
    __shared__ ushort As[128*64];
    __shared__ ushort Ws[128*64];
    int t = threadIdx.x, l = t & 63, wv = t >> 6;
    int m0 = blockIdx.y << 7, n0 = blockIdx.x << 7;
    int wm = (wv >> 1) << 6, wn = (wv & 1) << 6;
    int sr = t >> 1;
    int sh = (t & 1) << 5;
    f32x4 acc[4][4] = {};
    for (int k0 = 0; k0 < KP; k0 += 64) {
        if (k0) __syncthreads();
        if (AMODE == 1) {
            const ushort* ap = (const ushort*)Ain + (size_t)(m0 + sr) * lda + k0 + sh;
            #pragma unroll
            for (int u = 0; u < 4; u++)
                *(int4*)((char*)As + swz128(sr, (sh << 1) + (u << 4))) = *(const int4*)(ap + (u << 3));
        } else if (AMODE == 2) {
            const ushort* ap = (const ushort*)Ain + (size_t)(m0 + sr) * lda + k0 + sh;
            const ushort* gp = gmul + (size_t)(m0 + sr) * lda + k0 + sh;
            #pragma unroll
            for (int u = 0; u < 4; u++) {
                int4 av = *(const int4*)(ap + (u << 3));
                int4 gv = *(const int4*)(gp + (u << 3));
                ushort* au = (ushort*)&av; ushort* gu = (ushort*)&gv;
                short v8[8];
                #pragma unroll
                for (int e = 0; e < 8; e++) v8[e] = (short)f2bf(bf2f(au[e]) * bf2f(gu[e]));
                *(int4*)((char*)As + swz128(sr, (sh << 1) + (u << 4))) = *(int4*)v8;
            }
        } else {
            const float* ap = (const float*)Ain + (size_t)(m0 + sr) * lda;
            #pragma unroll
            for (int u = 0; u < 4; u++) {
                short v8[8];
                #pragma unroll
                for (int e = 0; e < 8; e++) {
                    int c = k0 + sh + (u << 3) + e;
                    v8[e] = (short)f2bf((c < lda) ? ap[c] : 0.f);
                }
                *(int4*)((char*)As + swz128(sr, (sh << 1) + (u << 4))) = *(int4*)v8;
            }
        }
        {
            const ushort* wp2 = Wt + (size_t)(n0 + sr) * KP + k0 + sh;
            #pragma unroll
            for (int u = 0; u < 4; u++)
                *(int4*)((char*)Ws + swz128(sr, (sh << 1) + (u << 4))) = *(const int4*)(wp2 + (u << 3));
        }
        __syncthreads();
        #pragma unroll
        for (int ks = 0; ks < 2; ks++) {
            int kb = (ks << 6) + ((l >> 4) << 4);
            bf16x8 a[4], b[4];
            #pragma unroll
            for (int x = 0; x < 4; x++) {
                a[x] = *(const bf16x8*)((char*)As + swz128(wm + (x << 4) + (l & 15), kb));
                b[x] = *(const bf16x8*)((char*)Ws + swz128(wn + (x << 4) + (l & 15), kb));
            }
            #pragma unroll
            for (int i = 0; i < 4; i++)
            #pragma unroll
            for (int j = 0; j < 4; j++)
                acc[i][j] = __builtin_amdgcn_mfma_f32_16x16x32_bf16(a[i], b[j], acc[i][j], 0, 0, 0);
        }
    }
    if (LNOUT) {
        #pragma unroll
        for (int mf = 0; mf < 4; mf++)
        #pragma unroll
        for (int nf = 0; nf < 4; nf++) {
            int col  = wn + (nf << 4) + (l & 15);
            int row0 = m0 + wm + (mf << 4) + ((l >> 4) << 2);
            float bb = bias ? bias[col] : 0.f;
            #pragma unroll
            for (int r = 0; r < 4; r++) {
                int row = row0 + r;
                size_t rrow = rtrans ? trow(row) : (size_t)row;
                acc[mf][nf][r] = acc[mf][nf][r] * alpha + bb + (res ? res[rrow * CDIM + col] : 0.f);
            }
        }
        float ps[4][4], pq[4][4];
        #pragma unroll
        for (int mf = 0; mf < 4; mf++)
        #pragma unroll
        for (int r = 0; r < 4; r++) {
            float s = 0.f, q = 0.f;
            #pragma unroll
            for (int nf = 0; nf < 4; nf++) { float v = acc[mf][nf][r]; s += v; q += v * v; }
            ps[mf][r] = s; pq[mf][r] = q;
        }
        #pragma unroll
        for (int off = 1; off < 16; off <<= 1)
        #pragma unroll
        for (int mf = 0; mf < 4; mf++)
        #pragma unroll
        for (int r = 0; r < 4; r++) {
            ps[mf][r] += __shfl_xor(ps[mf][r], off, 64);
            pq[mf][r] += __shfl_xor(pq[mf][r], off, 64);
        }
        __syncthreads();
        float* lnbuf = (float*)As;
        if ((l & 15) == 0) {
            #pragma unroll
            for (int mf = 0; mf < 4; mf++)
            #pragma unroll
            for (int r = 0; r < 4; r++) {
                int rl = wm + (mf << 4) + ((l >> 4) << 2) + r;
                lnbuf[(((wv & 1) << 7) + rl) * 2 + 0] = ps[mf][r];
                lnbuf[(((wv & 1) << 7) + rl) * 2 + 1] = pq[mf][r];
            }
        }
        __syncthreads();
        #pragma unroll
        for (int mf = 0; mf < 4; mf++)
        #pragma unroll
        for (int nf = 0; nf < 4; nf++) {
            int col  = wn + (nf << 4) + (l & 15);
            int row0 = m0 + wm + (mf << 4) + ((l >> 4) << 2);
            float lw = lnw2[col], lb = lnb2[col];
            #pragma unroll
            for (int r = 0; r < 4; r++) {
                int row = row0 + r;
                int rl  = wm + (mf << 4) + ((l >> 4) << 2) + r;
                float s  = lnbuf[rl * 2 + 0] + lnbuf[(256 + rl * 2) + 0];
                float q  = lnbuf[rl * 2 + 1] + lnbuf[(256 + rl * 2) + 1];
                float mean = s * (1.f/CDIM);
                float var  = q * (1.f/CDIM) - mean * mean;
                float rstd = rsqrtf(var + 1e-5f);
                float o = acc[mf][nf][r];
                size_t orow = otrans ? trow(row) : (size_t)row;
                ((float*)Cout)[orow * CDIM + col] = o;
                xln[orow * CDIM + col] = f2bf((o - mean) * rstd * lw + lb);
            }
        }
    } else {
        #pragma unroll
        for (int mf = 0; mf < 4; mf++)
        #pragma unroll
        for (int nf = 0; nf < 4; nf++) {
            int col  = n0 + wn + (nf << 4) + (l & 15);
            int row0 = m0 + wm + (mf << 4) + ((l >> 4) << 2);
            float bb = bias ? bias[col] : 0.f;
            #pragma unroll
            for (int r = 0; r < 4; r++) {
                int row = row0 + r;
                float v = acc[mf][nf][r] * alpha + bb;
                if (ACT == 1) v = fmaxf(v, 0.f);
                if (ACT == 2) v = 1.f / (1.f + __expf(-v));
                if (OUTMODE == 0) {
                    float o = v + (res ? res[(size_t)row * N + col] : 0.f);
                    ((float*)Cout)[(size_t)row * N + col] = o;
                } else if (OUTMODE == 1) {
                    ((ushort*)Cout)[(size_t)row * N + col] = f2bf(v);
                } else {
                    size_t orow = otrans ? trow(row) : (size_t)row;
                    size_t rrow = rtrans ? trow(row) : (size_t)row;
                    float o = v + (res ? res[rrow * N + col] : 0.f);
                    ((float*)Cout)[orow * N + col] = o;
                }
            }
        }
    }
}

// ------- q,k,v,g: M=64 tile (As 16KB + Ws 32KB = 48KB -> 3 blocks/CU), 2304 blocks -------
__global__ __launch_bounds__(256) void qkv4_gemm(
    const ushort* __restrict__ A, const ushort* __restrict__ wt4,
    ushort* __restrict__ qo, ushort* __restrict__ ko, ushort* __restrict__ vt,
    ushort* __restrict__ go, const float* __restrict__ bg,
    float scale_q, float scale_k)
{
    __shared__ ushort As[64*128];
    __shared__ ushort Ws[128*128];
    int t = threadIdx.x, l = t & 63, wv = t >> 6;
    int m0 = blockIdx.x << 6;
    int wm = (wv >> 1) << 5;
    int wn = (wv & 1) << 6;
    {
        int sr = t >> 2, scb = (t & 3) << 6;
        const ushort* ap = A + (size_t)(m0 + sr) * CDIM + (scb >> 1);
        #pragma unroll
        for (int u = 0; u < 4; u++)
            *(int4*)((char*)As + swz256(sr, scb + (u << 4))) = *(const int4*)(ap + (u << 3));
    }
    for (int comp = 0; comp < 4; comp++) {
        if (comp) __syncthreads();
        {
            int sr = t >> 1, scb = (t & 1) << 7;
            const ushort* wp2 = wt4 + (size_t)comp * 16384 + (size_t)sr * CDIM + (scb >> 1);
            #pragma unroll
            for (int u = 0; u < 8; u++)
                *(int4*)((char*)Ws + swz256(sr, scb + (u << 4))) = *(const int4*)(wp2 + (u << 3));
        }
        __syncthreads();
        f32x4 acc[2][4] = {};
        #pragma unroll
        for (int ks = 0; ks < 4; ks++) {
            int kb = (ks << 6) + ((l >> 4) << 4);
            bf16x8 a[2], b[4];
            #pragma unroll
            for (int x = 0; x < 2; x++)
                a[x] = *(const bf16x8*)((char*)As + swz256(wm + (x << 4) + (l & 15), kb));
            #pragma unroll
            for (int x = 0; x < 4; x++)
                b[x] = *(const bf16x8*)((char*)Ws + swz256(wn + (x << 4) + (l & 15), kb));
            #pragma unroll
            for (int i = 0; i < 2; i++)
            #pragma unroll
            for (int j = 0; j < 4; j++)
                acc[i][j] = __builtin_amdgcn_mfma_f32_16x16x32_bf16(a[i], b[j], acc[i][j], 0, 0, 0);
        }
        #pragma unroll
        for (int mf = 0; mf < 2; mf++)
        #pragma unroll
        for (int nf = 0; nf < 4; nf++) {
            int col  = wn + (nf << 4) + (l & 15);
            int row0 = m0 + wm + (mf << 4) + ((l >> 4) << 2);
            if (comp == 0) {
                #pragma unroll
                for (int r = 0; r < 4; r++)
                    qo[(size_t)(row0 + r) * CDIM + col] = f2bf(acc[mf][nf][r] * scale_q);
            } else if (comp == 1) {
                #pragma unroll
                for (int r = 0; r < 4; r++)
                    ko[(size_t)(row0 + r) * CDIM + col] = f2bf(acc[mf][nf][r] * scale_k);
            } else if (comp == 2) {
                ushort4 pk;
                #pragma unroll
                for (int r = 0; r < 4; r++) ((ushort*)&pk)[r] = f2bf(acc[mf][nf][r]);
                int n = row0 / LDIM, j = row0 % LDIM;
                *(ushort4*)&vt[((size_t)(col >> 5) * 12288 + (size_t)n * 32 + (col & 31)) * 384 + j] = pk;
            } else {
                float bb = bg[col];
                #pragma unroll
                for (int r = 0; r < 4; r++) {
                    float v = acc[mf][nf][r] + bb;
                    go[(size_t)(row0 + r) * CDIM + col] = f2bf(1.f / (1.f + __expf(-v)));
                }
            }
        }
    }
}

// ------- tied scores (verified round-7 3D grid): partial[cz,h,i,j] -------
__global__ __launch_bounds__(256) void score128(const ushort* __restrict__ Q,
    const ushort* __restrict__ Kb, float* __restrict__ partial)
{
    __shared__ ushort As[128*128];
    __shared__ ushort Bs[128*128];
    int t = threadIdx.x, l = t & 63, wv = t >> 6;
    int ti = blockIdx.x / 3, tj = blockIdx.x % 3;
    int h = blockIdx.y, cz = blockIdx.z;
    int i0 = ti << 7, j0 = tj << 7;
    int wm = (wv >> 1) << 6, wn = (wv & 1) << 6;
    int sr = t >> 1, half = t & 1;
    f32x4 acc[4][4] = {};
    for (int it = 0; it < 12; it++) {
        if (it) __syncthreads();
        int nb = cz * 48 + (it << 2);
        #pragma unroll
        for (int e = 0; e < 2; e++) {
            int nq = (half << 1) + e;
            const ushort* qp = Q  + ((size_t)(nb + nq) * LDIM + i0 + sr) * CDIM + (h << 5);
            const ushort* kp = Kb + ((size_t)(nb + nq) * LDIM + j0 + sr) * CDIM + (h << 5);
            *(int4*)((char*)As + swz256(sr, (nq << 6) +  0)) = *(const int4*)qp;
            *(int4*)((char*)As + swz256(sr, (nq << 6) + 16)) = *(const int4*)(qp + 8);
            *(int4*)((char*)As + swz256(sr, (nq << 6) + 32)) = *(const int4*)(qp + 16);
            *(int4*)((char*)As + swz256(sr, (nq << 6) + 48)) = *(const int4*)(qp + 24);
            *(int4*)((char*)Bs + swz256(sr, (nq << 6) +  0)) = *(const int4*)kp;
            *(int4*)((char*)Bs + swz256(sr, (nq << 6) + 16)) = *(const int4*)(kp + 8);
            *(int4*)((char*)Bs + swz256(sr, (nq << 6) + 32)) = *(const int4*)(kp + 16);
            *(int4*)((char*)Bs + swz256(sr, (nq << 6) + 48)) = *(const int4*)(kp + 24);
        }
        __syncthreads();
        #pragma unroll
        for (int ks = 0; ks < 4; ks++) {
            int kb = (ks << 6) + ((l >> 4) << 4);
            bf16x8 a[4], b[4];
            #pragma unroll
            for (int x = 0; x < 4; x++) {
                a[x] = *(const bf16x8*)((char*)As + swz256(wm + (x << 4) + (l & 15), kb));
                b[x] = *(const bf16x8*)((char*)Bs + swz256(wn + (x << 4) + (l & 15), kb));
            }
            #pragma unroll
            for (int i = 0; i < 4; i++)
            #pragma unroll
            for (int j = 0; j < 4; j++)
                acc[i][j] = __builtin_amdgcn_mfma_f32_16x16x32_bf16(a[i], b[j], acc[i][j], 0, 0, 0);
        }
    }
    #pragma unroll
    for (int mf = 0; mf < 4; mf++)
    #pragma unroll
    for (int nf = 0; nf < 4; nf++) {
        int j = j0 + wn + (nf << 4) + (l & 15);
        int i = i0 + wm + (mf << 4) + ((l >> 4) << 2);
        #pragma unroll
        for (int r = 0; r < 4; r++)
            partial[((size_t)(cz*HN + h)*LDIM + i + r)*LDIM + j] = acc[mf][nf][r];
    }
}

// ---------------- softmax over j (chunk reduce + bias) -> bf16 ----------------
__global__ __launch_bounds__(64) void softmax_kernel(
    const float* __restrict__ partial, const float* __restrict__ battn, ushort* __restrict__ attn)
{
    int hi = blockIdx.x;
    int l = threadIdx.x;
    float s[6];
    #pragma unroll
    for (int u = 0; u < 6; u++) {
        size_t idx = (size_t)hi * LDIM + l + (u << 6);
        float v = battn[idx];
        #pragma unroll
        for (int c = 0; c < NCHUNK; c++) v += partial[(size_t)c * HN * LL + idx];
        s[u] = v;
    }
    float m = s[0];
    #pragma unroll
    for (int u = 1; u < 6; u++) m = fmaxf(m, s[u]);
    #pragma unroll
    for (int off = 32; off; off >>= 1) m = fmaxf(m, __shfl_xor(m, off, 64));
    float sum = 0.f;
    #pragma unroll
    for (int u = 0; u < 6; u++) { s[u] = __expf(s[u] - m); sum += s[u]; }
    #pragma unroll
    for (int off = 32; off; off >>= 1) sum += __shfl_xor(sum, off, 64);
    float inv = 1.f / sum;
    #pragma unroll
    for (int u = 0; u < 6; u++) attn[(size_t)hi * LDIM + l + (u << 6)] = f2bf(s[u] * inv);
}

// ------- PV per-head GEMM (BK=64): pvout[(n,i),h*32+d] -------
__global__ __launch_bounds__(256) void pvg_gemm(const ushort* __restrict__ attn,
    const ushort* __restrict__ vt, ushort* __restrict__ pvout)
{
    __shared__ ushort As[128*64];
    __shared__ ushort Ws[128*64];
    int t = threadIdx.x, l = t & 63, wv = t >> 6;
    int n0 = blockIdx.x << 7;
    int i0 = blockIdx.y << 7;
    int h  = blockIdx.z;
    const ushort* abase = attn + (size_t)h * LL;
    const ushort* bbase = vt + (size_t)h * VTPLANE;
    int wm = (wv >> 1) << 6, wn = (wv & 1) << 6;
    int sr = t >> 1, sh = (t & 1) << 5;
    f32x4 acc[4][4] = {};
    for (int k0 = 0; k0 < LDIM; k0 += 64) {
        if (k0) __syncthreads();
        {
            const ushort* ap = abase + (size_t)(i0 + sr) * LDIM + k0 + sh;
            const ushort* bp = bbase + (size_t)(n0 + sr) * LDIM + k0 + sh;
            #pragma unroll
            for (int u = 0; u < 4; u++) {
                *(int4*)((char*)As + swz128(sr, (sh << 1) + (u << 4))) = *(const int4*)(ap + (u << 3));
                *(int4*)((char*)Ws + swz128(sr, (sh << 1) + (u << 4))) = *(const int4*)(bp + (u << 3));
            }
        }
        __syncthreads();
        #pragma unroll
        for (int ks = 0; ks < 2; ks++) {
            int kb = (ks << 6) + ((l >> 4) << 4);
            bf16x8 a[4], b[4];
            #pragma unroll
            for (int x = 0; x < 4; x++) {
                a[x] = *(const bf16x8*)((char*)As + swz128(wm + (x << 4) + (l & 15), kb));
                b[x] = *(const bf16x8*)((char*)Ws + swz128(wn + (x << 4) + (l & 15), kb));
            }
            #pragma unroll
            for (int i = 0; i < 4; i++)
            #pragma unroll
            for (int j = 0; j < 4; j++)
                acc[i][j] = __builtin_amdgcn_mfma_f32_16x16x32_bf16(a[i], b[j], acc[i][j], 0, 0, 0);
        }
    }
    #pragma unroll
    for (int mf = 0; mf < 4; mf++)
    #pragma unroll
    for (int nf = 0; nf < 4; nf++) {
        int col  = n0 + wn + (nf << 4) + (l & 15);
        int row0 = i0 + wm + (mf << 4) + ((l >> 4) << 2);
        int n = col >> 5, d = col & 31;
        #pragma unroll
        for (int r = 0; r < 4; r++) {
            int i = row0 + r;
            pvout[((size_t)n * LDIM + i) * CDIM + (h << 5) + d] = f2bf(acc[mf][nf][r]);
        }
    }
}

extern "C" void kernel_launch(void* const* d_in, const int* in_sizes, int n_in,
                              void* d_out, int out_size, void* d_ws, size_t ws_size,
                              hipStream_t stream)
{
    const float* pair     = (const float*)d_in[0];
    const float* rbf_feat = (const float*)d_in[1];
    const float* emb_b    = (const float*)d_in[3];
    const float* proj_b   = (const float*)d_in[5];
    const float* ff_ln_w  = (const float*)d_in[30];
    const float* ff_ln_b  = (const float*)d_in[31];
    const float* ff_b1    = (const float*)d_in[33];
    const float* ff_b2    = (const float*)d_in[35];
    float* out = (float*)d_out;

    ushort* R0 = (ushort*)d_ws;
    ushort* R1 = R0 + (size_t)LL*CDIM;
    ushort* R2 = R1 + (size_t)LL*CDIM;
    ushort* R3 = R2 + (size_t)LL*CDIM;
    float*  partialb = (float*)(R3 + (size_t)LL*CDIM);
    float*  battn_r  = partialb + (size_t)NCHUNK*HN*LL;
    float*  battn_c  = battn_r  + (size_t)HN*LL;
    ushort* attn_bf  = (ushort*)(battn_c + (size_t)HN*LL);
    ushort* wt       = attn_bf + (size_t)HN*LL;

    size_t need_bytes = (size_t)4*LL*CDIM*2 + ((size_t)NCHUNK*HN*LL + 2*(size_t)HN*LL)*4
                      + (size_t)HN*LL*2 + (size_t)262144*2;
    if (ws_size < need_bytes) return;

    const size_t WS = 16384;
    ushort* wt_emb  = wt;
    ushort* wt_proj = wt + WS;
    ushort* wt_ff1  = wt + 12*WS;
    ushort* wt_ff2  = wt + 12*WS + 32768;

    const float SCALE = 0.17677669529663687f;  // 32^-0.5

    wprep_kernel<<<dim3(128, 14), 256, 0, stream>>>(wt,
        (const float*)d_in[2], (const float*)d_in[4],
        (const float*)d_in[10], (const float*)d_in[11], (const float*)d_in[12],
        (const float*)d_in[14], (const float*)d_in[16],
        (const float*)d_in[22], (const float*)d_in[23], (const float*)d_in[24],
        (const float*)d_in[26], (const float*)d_in[28],
        (const float*)d_in[32], (const float*)d_in[34]);

    // emb hidden bf16 -> R3
    mgemm64<1,0,1,0><<<dim3(1,1152), 256, 0, stream>>>(rbf_feat, wt_emb, emb_b, nullptr, nullptr, R3,
        nullptr, nullptr, nullptr, 128, 128, 36, 1.f, 0, 0);
    // fused proj + dual battn: rbf never materialized
    proj_battn_gemm<<<1152, 256, 0, stream>>>(R3, wt_proj, proj_b,
        (const float*)d_in[8],  (const float*)d_in[9],  (const float*)d_in[13],
        (const float*)d_in[20], (const float*)d_in[21], (const float*)d_in[25],
        battn_r, battn_c);

    // initial row-pass xln (transposed frame) -> R3
    lnpack_kernel<<<LL/4, 256, 0, stream>>>(pair, R3, (const float*)d_in[6], (const float*)d_in[7], 1);

    ushort* XLN = R3;
    for (int pass = 0; pass < 2; pass++) {
        const float* const* wp = (const float* const*)(d_in + (pass ? 18 : 6));
        int trans = pass ? 0 : 1;
        const float* P = pass ? (const float*)out : pair;
        const float* battnb = pass ? battn_c : battn_r;
        int ws0 = pass ? 7 : 2;
        const float* nlw = pass ? ff_ln_w : (const float*)d_in[18];
        const float* nlb = pass ? ff_ln_b : (const float*)d_in[19];
        ushort* Qb   = R0;
        ushort* Kb2  = pass ? R3 : R1;
        ushort* VTb  = R2;
        ushort* PVb  = R0;
        ushort* XLNn = pass ? R3 : R1;
        qkv4_gemm<<<LL/64, 256, 0, stream>>>(XLN, wt + ws0*WS, Qb, Kb2, VTb, XLN, wp[9], SCALE, 1.f/LDIM);
        score128<<<dim3(9, HN, NCHUNK), 256, 0, stream>>>(Qb, Kb2, partialb);
        softmax_kernel<<<HN*LDIM, 64, 0, stream>>>(partialb, battnb, attn_bf);
        pvg_gemm<<<dim3(96, 3, 4), 256, 0, stream>>>(attn_bf, VTb, PVb);
        mgemm64<0,2,3,1><<<dim3(1,1152), 256, 0, stream>>>(PVb, wt + (ws0+4)*WS, wp[11], XLN, P, out,
            nlw, nlb, XLNn, 128, 128, 128, 1.f, trans, trans);
        XLN = XLNn;
    }

    // FFN: out += relu(xln@w1+b1)@w2+b2  (h1 bf16 [LL][256] spans R0+R1)
    mgemm64<1,1,1,0><<<dim3(2,1152), 256, 0, stream>>>(XLN, wt_ff1, ff_b1, nullptr, nullptr, R0,
        nullptr, nullptr, nullptr, 256, 128, 128, 1.f, 0, 0);
    mgemm64<0,1,0,0><<<dim3(1,1152), 256, 0, stream>>>(R0, wt_ff2, ff_b2, nullptr, out, out,
        nullptr, nullptr, nullptr, 128, 256, 256, 1.f, 0, 0);
}